// Round 4
// baseline (1164.802 us; speedup 1.0000x reference)
//
#include <hip/hip_runtime.h>
#include <math.h>

#define HID 64
#define DF  128
#define GS  8   // edge-slice lanes per node in gather

__device__ __forceinline__ float silu_f(float v) {
    return v / (1.0f + __expf(-v));
}

// ---------------------------------------------------------------------------
// Weight transposes: [k][f]-major so unrolled per-lane loops read weights at
// wave-uniform consecutive addresses (s_load batches).
// ---------------------------------------------------------------------------
__global__ void prep_weights(const float* __restrict__ We1, const float* __restrict__ We2,
                             const float* __restrict__ Wh1, const float* __restrict__ Wh2,
                             float* __restrict__ Wt1, float* __restrict__ Wt2,
                             float* __restrict__ Wht1, float* __restrict__ Wht2) {
    int i = blockIdx.x * 256 + threadIdx.x;
    if (i < 257 * 64) {
        int k = i >> 6, f = i & 63;
        Wt1[i] = We1[f * 257 + k];
        return;
    }
    int j = i - 257 * 64;
    if (j < 64 * 64) {
        int k = j >> 6, f = j & 63;
        Wt2[j] = We2[f * 64 + k];
        return;
    }
    j -= 64 * 64;
    if (j < 192 * 64) {
        int k = j >> 6, f = j & 63;
        Wht1[j] = Wh1[f * 192 + k];
        return;
    }
    j -= 192 * 64;
    if (j < 64 * 128) {
        int f = j >> 7, c = j & 127;
        Wht2[j] = Wh2[c * 64 + f];
        return;
    }
}

// ---------------------------------------------------------------------------
// CSR build
// ---------------------------------------------------------------------------
__global__ __launch_bounds__(256) void count_kernel(const int* __restrict__ dst,
                                                    int* __restrict__ cnt,
                                                    int* __restrict__ rank, int E) {
    int e = blockIdx.x * 256 + threadIdx.x;
    if (e >= E) return;
    int r = atomicAdd(&cnt[dst[e]], 1);
    if (rank) rank[e] = r;
}

__global__ __launch_bounds__(1024) void scan1(const int* __restrict__ cnt,
                                              int* __restrict__ off,
                                              int* __restrict__ bsum, int N) {
    __shared__ int sm[1024];
    int tid = threadIdx.x;
    int i = blockIdx.x * 1024 + tid;
    int v = (i < N) ? cnt[i] : 0;
    sm[tid] = v;
    __syncthreads();
    for (int ofs = 1; ofs < 1024; ofs <<= 1) {
        int t = (tid >= ofs) ? sm[tid - ofs] : 0;
        __syncthreads();
        sm[tid] += t;
        __syncthreads();
    }
    if (i < N) off[i] = sm[tid] - v;
    if (tid == 1023) bsum[blockIdx.x] = sm[1023];
}

__global__ void scan2(const int* __restrict__ bsum, int* __restrict__ bofs, int Nb) {
    if (threadIdx.x == 0) {
        int s = 0;
        for (int b = 0; b < Nb; ++b) { bofs[b] = s; s += bsum[b]; }
    }
}

__global__ __launch_bounds__(256) void scan3(int* __restrict__ off,
                                             const int* __restrict__ bofs,
                                             int N, int E) {
    int i = blockIdx.x * 256 + threadIdx.x;
    if (i > N) return;
    if (i == N) off[N] = E;
    else off[i] += bofs[i >> 10];
}

__global__ __launch_bounds__(256) void deghist(const int* __restrict__ cnt,
                                               int* __restrict__ dcnt,
                                               int* __restrict__ dnr, int N) {
    int n = blockIdx.x * 256 + threadIdx.x;
    if (n >= N) return;
    int b = min(cnt[n], 63);
    dnr[n] = atomicAdd(&dcnt[b], 1);
}

__global__ void degscan(const int* __restrict__ dcnt, int* __restrict__ dofs) {
    if (threadIdx.x == 0) {
        int s = 0;
        for (int b = 0; b < 64; ++b) { dofs[b] = s; s += dcnt[b]; }
    }
}

__global__ __launch_bounds__(256) void degscatter(const int* __restrict__ cnt,
                                                  const int* __restrict__ dnr,
                                                  const int* __restrict__ dofs,
                                                  int* __restrict__ nodeorder, int N) {
    int n = blockIdx.x * 256 + threadIdx.x;
    if (n >= N) return;
    int b = min(cnt[n], 63);
    nodeorder[dofs[b] + dnr[n]] = n;
}

// csr_src[off[dst[e]] + rank[e]] = src[e]
__global__ __launch_bounds__(256) void scatter_src(const int* __restrict__ dst,
                                                   const int* __restrict__ srcI,
                                                   const int* __restrict__ rank,
                                                   const int* __restrict__ off,
                                                   int* __restrict__ csr_src, int E) {
    int e = blockIdx.x * 256 + threadIdx.x;
    if (e >= E) return;
    csr_src[off[dst[e]] + rank[e]] = srcI[e];
}

// ---------------------------------------------------------------------------
// node_pre (wave-feature-split): 4 waves over 64 nodes; wave w does 16 feats.
// ---------------------------------------------------------------------------
__global__ __launch_bounds__(256) void node_pre(const float* __restrict__ h,
                                                const float* __restrict__ Wt1,
                                                float* __restrict__ Ps,
                                                float* __restrict__ Pd, int N) {
    int lane = threadIdx.x & 63;
    int w = __builtin_amdgcn_readfirstlane(threadIdx.x >> 6);
    int n = blockIdx.x * 64 + lane;
    if (n >= N) return;
    int f0 = w * 16;
    float accS[16], accD[16];
#pragma unroll
    for (int j = 0; j < 16; ++j) { accS[j] = 0.f; accD[j] = 0.f; }
    const float4* row = (const float4*)(h + (size_t)n * DF);
    for (int k4 = 0; k4 < DF / 4; ++k4) {
        float4 v = row[k4];
        float hv4[4] = {v.x, v.y, v.z, v.w};
#pragma unroll
        for (int jj = 0; jj < 4; ++jj) {
            int k = k4 * 4 + jj;
            float hv = hv4[jj];
#pragma unroll
            for (int j = 0; j < 16; ++j) {
                accS[j] = fmaf(hv, Wt1[k * HID + f0 + j], accS[j]);
                accD[j] = fmaf(hv, Wt1[(DF + k) * HID + f0 + j], accD[j]);
            }
        }
    }
    float4* ps = (float4*)(Ps + (size_t)n * HID + f0);
    float4* pd = (float4*)(Pd + (size_t)n * HID + f0);
#pragma unroll
    for (int j4 = 0; j4 < 4; ++j4) {
        ps[j4] = make_float4(accS[4 * j4], accS[4 * j4 + 1], accS[4 * j4 + 2], accS[4 * j4 + 3]);
        pd[j4] = make_float4(accD[4 * j4], accD[4 * j4 + 1], accD[4 * j4 + 2], accD[4 * j4 + 3]);
    }
}

// ---------------------------------------------------------------------------
// Gather: GS=8 lanes per dst node; each lane recomputes the edge MLP for
// every-GS'th edge. acc[64] lives in LDS (transposed [f][tid] layout -> bank
// = tid%32, conflict-free; lane-private ds_add_f32 per edge). m[64] stays in
// registers -> no scratch spills. 8-lane shfl_xor tree combines at the end.
// ---------------------------------------------------------------------------
__global__ __launch_bounds__(256, 2) void gather_kernel(
    const int* __restrict__ csr_src, const int* __restrict__ off,
    const int* __restrict__ nodeorder, const float* __restrict__ x,
    const float* __restrict__ Ps, const float* __restrict__ Pd,
    const float* __restrict__ Wt1, const float* __restrict__ Wt2,
    const float* __restrict__ be1, const float* __restrict__ be2,
    const float* __restrict__ ln_g, const float* __restrict__ ln_b,
    const float* __restrict__ Wx, const float* __restrict__ bx,
    const float* __restrict__ Wg, const float* __restrict__ bg,
    float* __restrict__ agg_h, float* __restrict__ agg_x, int N) {
    __shared__ float accL[HID * 256];   // [f][tid] transposed, exactly 64 KB
    const int tid = threadIdx.x;
#pragma unroll
    for (int f = 0; f < HID; ++f) accL[f * 256 + tid] = 0.f;

    int gid = blockIdx.x * 256 + tid;
    int slot = gid >> 3, sub = gid & (GS - 1);
    if (slot >= N) return;   // whole 8-lane group uniform -> safe
    int n = nodeorder[slot];
    int beg = off[n], end = off[n + 1];

    float xd0 = x[n * 3], xd1 = x[n * 3 + 1], xd2 = x[n * 3 + 2];
    const float* colW = Wt1 + 256 * HID;  // We1[:,256] (d_sq column)
    const float4* pd = (const float4*)(Pd + (size_t)n * HID);

    float ax0 = 0.f, ax1 = 0.f, ax2 = 0.f;

    for (int i = beg + sub; i < end; i += GS) {
        int s = csr_src[i];
        float r0 = x[s * 3] - xd0, r1 = x[s * 3 + 1] - xd1, r2 = x[s * 3 + 2] - xd2;
        float dsq = r0 * r0 + r1 * r1 + r2 * r2;
        float inv = 1.0f / (sqrtf(dsq) + 1e-8f);
        float rn0 = r0 * inv, rn1 = r1 * inv, rn2 = r2 * inv;

        float m[HID];
#pragma unroll
        for (int f = 0; f < HID; ++f) m[f] = be2[f];

        const float4* ps = (const float4*)(Ps + (size_t)s * HID);
#pragma unroll
        for (int k4 = 0; k4 < HID / 4; ++k4) {
            float4 a = ps[k4];
            float4 b = pd[k4];
            float av[4] = {a.x, a.y, a.z, a.w};
            float bv[4] = {b.x, b.y, b.z, b.w};
#pragma unroll
            for (int j = 0; j < 4; ++j) {
                int k = 4 * k4 + j;
                float zk = silu_f(av[j] + bv[j] + be1[k] + dsq * colW[k]);
#pragma unroll
                for (int f = 0; f < HID; ++f) m[f] = fmaf(zk, Wt2[k * HID + f], m[f]);
            }
        }
#pragma unroll
        for (int f = 0; f < HID; ++f) m[f] = silu_f(m[f]);

        // LayerNorm
        float mu = 0.f;
#pragma unroll
        for (int f = 0; f < HID; ++f) mu += m[f];
        mu *= (1.0f / HID);
        float var = 0.f;
#pragma unroll
        for (int f = 0; f < HID; ++f) {
            float t = m[f] - mu;
            var = fmaf(t, t, var);
        }
        var *= (1.0f / HID);
        float rstd = 1.0f / sqrtf(var + 1e-5f);
#pragma unroll
        for (int f = 0; f < HID; ++f) m[f] = (m[f] - mu) * rstd * ln_g[f] + ln_b[f];

        // gates
        float dotg = 0.f, dotx = 0.f;
#pragma unroll
        for (int f = 0; f < HID; ++f) {
            dotg = fmaf(m[f], Wg[f], dotg);
            dotx = fmaf(m[f], Wx[f], dotx);
        }
        float alpha = 1.0f / (1.0f + __expf(-(dotg + bg[0])));
        float ta = __expf(2.0f * fmaf(alpha, dotx, bx[0]));
        float cw = 1.0f - 2.0f / (ta + 1.0f);

        // accumulate gated message into LDS (lane-private ds_add_f32)
#pragma unroll
        for (int f = 0; f < HID; ++f)
            atomicAdd(&accL[f * 256 + tid], m[f] * alpha);
        ax0 = fmaf(rn0, cw, ax0);
        ax1 = fmaf(rn1, cw, ax1);
        ax2 = fmaf(rn2, cw, ax2);
    }

    // read own partials back (conflict-free) and combine the 8 sub-lanes
    float acc[HID];
#pragma unroll
    for (int f = 0; f < HID; ++f) acc[f] = accL[f * 256 + tid];
#pragma unroll
    for (int d = 1; d < GS; d <<= 1) {
#pragma unroll
        for (int f = 0; f < HID; ++f) acc[f] += __shfl_xor(acc[f], d, 64);
        ax0 += __shfl_xor(ax0, d, 64);
        ax1 += __shfl_xor(ax1, d, 64);
        ax2 += __shfl_xor(ax2, d, 64);
    }

    if (sub == 0) {
        float4* ah = (float4*)(agg_h + (size_t)n * HID);
#pragma unroll
        for (int f4 = 0; f4 < HID / 4; ++f4)
            ah[f4] = make_float4(acc[4 * f4], acc[4 * f4 + 1], acc[4 * f4 + 2], acc[4 * f4 + 3]);
        agg_x[n * 3 + 0] = ax0;
        agg_x[n * 3 + 1] = ax1;
        agg_x[n * 3 + 2] = ax2;
    }
}

// ---------------------------------------------------------------------------
// Fallback edge kernel (atomic aggregation) — only if ws too small for CSR.
// ---------------------------------------------------------------------------
__global__ __launch_bounds__(256) void edge_kernel_atomic(
    const int* __restrict__ src, const int* __restrict__ dst,
    const float* __restrict__ x,
    const float* __restrict__ Ps, const float* __restrict__ Pd,
    const float* __restrict__ Wt1, const float* __restrict__ Wt2,
    const float* __restrict__ be1, const float* __restrict__ be2,
    const float* __restrict__ ln_g, const float* __restrict__ ln_b,
    const float* __restrict__ Wx, const float* __restrict__ bx,
    const float* __restrict__ Wg, const float* __restrict__ bg,
    float* __restrict__ agg_h, float* __restrict__ agg_x, int E) {
    int e = blockIdx.x * 256 + threadIdx.x;
    if (e >= E) return;
    int s = src[e], d = dst[e];
    float r0 = x[s * 3] - x[d * 3], r1 = x[s * 3 + 1] - x[d * 3 + 1], r2 = x[s * 3 + 2] - x[d * 3 + 2];
    float dsq = r0 * r0 + r1 * r1 + r2 * r2;
    float inv = 1.0f / (sqrtf(dsq) + 1e-8f);
    float rn0 = r0 * inv, rn1 = r1 * inv, rn2 = r2 * inv;
    float z[HID];
    const float4* ps = (const float4*)(Ps + (size_t)s * HID);
    const float4* pd = (const float4*)(Pd + (size_t)d * HID);
    const float* colW = Wt1 + 256 * HID;
#pragma unroll
    for (int f4 = 0; f4 < HID / 4; ++f4) {
        float4 a = ps[f4];
        float4 b = pd[f4];
        float av[4] = {a.x, a.y, a.z, a.w};
        float bv[4] = {b.x, b.y, b.z, b.w};
#pragma unroll
        for (int j = 0; j < 4; ++j) {
            int f = 4 * f4 + j;
            z[f] = silu_f(av[j] + bv[j] + be1[f] + dsq * colW[f]);
        }
    }
    float m[HID];
#pragma unroll
    for (int f = 0; f < HID; ++f) m[f] = be2[f];
#pragma unroll
    for (int k = 0; k < HID; ++k) {
        float zv = z[k];
#pragma unroll
        for (int f = 0; f < HID; ++f) m[f] = fmaf(zv, Wt2[k * HID + f], m[f]);
    }
#pragma unroll
    for (int f = 0; f < HID; ++f) m[f] = silu_f(m[f]);
    float mu = 0.f;
#pragma unroll
    for (int f = 0; f < HID; ++f) mu += m[f];
    mu *= (1.0f / HID);
    float var = 0.f;
#pragma unroll
    for (int f = 0; f < HID; ++f) {
        float t = m[f] - mu;
        var = fmaf(t, t, var);
    }
    var *= (1.0f / HID);
    float rstd = 1.0f / sqrtf(var + 1e-5f);
#pragma unroll
    for (int f = 0; f < HID; ++f) m[f] = (m[f] - mu) * rstd * ln_g[f] + ln_b[f];
    float dotg = 0.f, dotx = 0.f;
#pragma unroll
    for (int f = 0; f < HID; ++f) {
        dotg = fmaf(m[f], Wg[f], dotg);
        dotx = fmaf(m[f], Wx[f], dotx);
    }
    float alpha = 1.0f / (1.0f + __expf(-(dotg + bg[0])));
    float ta = __expf(2.0f * fmaf(alpha, dotx, bx[0]));
    float cw = 1.0f - 2.0f / (ta + 1.0f);
    float* ah = agg_h + (size_t)d * HID;
#pragma unroll
    for (int f = 0; f < HID; ++f) atomicAdd(&ah[f], m[f] * alpha);
    atomicAdd(&agg_x[d * 3 + 0], rn0 * cw);
    atomicAdd(&agg_x[d * 3 + 1], rn1 * cw);
    atomicAdd(&agg_x[d * 3 + 2], rn2 * cw);
}

// ---------------------------------------------------------------------------
// node_kernel (wave-feature-split, LDS hh exchange)
// ---------------------------------------------------------------------------
__global__ __launch_bounds__(256) void node_kernel(
    const float* __restrict__ h, const float* __restrict__ x,
    const float* __restrict__ agg_h, const float* __restrict__ agg_x,
    const int* __restrict__ degI,
    const float* __restrict__ Wht1, const float* __restrict__ Wht2,
    const float* __restrict__ bh1, const float* __restrict__ bh2,
    float* __restrict__ out, int N) {
    __shared__ float hh[64 * 65];
    int lane = threadIdx.x & 63;
    int w = __builtin_amdgcn_readfirstlane(threadIdx.x >> 6);
    int n = blockIdx.x * 64 + lane;

    if (n < N) {
        int f0 = w * 16;
        float t[16];
#pragma unroll
        for (int j = 0; j < 16; ++j) t[j] = bh1[f0 + j];
        const float4* rowH = (const float4*)(h + (size_t)n * DF);
        for (int k4 = 0; k4 < DF / 4; ++k4) {
            float4 v = rowH[k4];
            float hv4[4] = {v.x, v.y, v.z, v.w};
#pragma unroll
            for (int jj = 0; jj < 4; ++jj) {
                int k = k4 * 4 + jj;
                float hv = hv4[jj];
#pragma unroll
                for (int j = 0; j < 16; ++j) t[j] = fmaf(hv, Wht1[k * HID + f0 + j], t[j]);
            }
        }
        const float4* rowA = (const float4*)(agg_h + (size_t)n * HID);
        for (int k4 = 0; k4 < HID / 4; ++k4) {
            float4 v = rowA[k4];
            float hv4[4] = {v.x, v.y, v.z, v.w};
#pragma unroll
            for (int jj = 0; jj < 4; ++jj) {
                int k = DF + k4 * 4 + jj;
                float hv = hv4[jj];
#pragma unroll
                for (int j = 0; j < 16; ++j) t[j] = fmaf(hv, Wht1[k * HID + f0 + j], t[j]);
            }
        }
#pragma unroll
        for (int j = 0; j < 16; ++j) hh[lane * 65 + f0 + j] = silu_f(t[j]);
    }
    __syncthreads();
    if (n >= N) return;

    int c0 = w * 32;
    float o[32];
#pragma unroll
    for (int j = 0; j < 32; ++j) o[j] = bh2[c0 + j];
    for (int k = 0; k < HID; ++k) {
        float hv = hh[lane * 65 + k];
#pragma unroll
        for (int j = 0; j < 32; ++j) o[j] = fmaf(hv, Wht2[k * DF + c0 + j], o[j]);
    }
    float* oh = out + (size_t)n * DF + c0;
    const float* hrow = h + (size_t)n * DF + c0;
#pragma unroll
    for (int j4 = 0; j4 < 8; ++j4) {
        float4 hv = ((const float4*)hrow)[j4];
        float4 r;
        r.x = hv.x + o[4 * j4];
        r.y = hv.y + o[4 * j4 + 1];
        r.z = hv.z + o[4 * j4 + 2];
        r.w = hv.w + o[4 * j4 + 3];
        ((float4*)oh)[j4] = r;
    }
    if (w == 0) {
        float dv = (float)degI[n];
        float invd = 1.0f / fmaxf(dv, 1.0f);
        float* ox = out + (size_t)N * DF + (size_t)n * 3;
        ox[0] = x[n * 3 + 0] + agg_x[n * 3 + 0] * invd;
        ox[1] = x[n * 3 + 1] + agg_x[n * 3 + 1] * invd;
        ox[2] = x[n * 3 + 2] + agg_x[n * 3 + 2] * invd;
    }
}

extern "C" void kernel_launch(void* const* d_in, const int* in_sizes, int n_in,
                              void* d_out, int out_size, void* d_ws, size_t ws_size,
                              hipStream_t stream) {
    const float* h    = (const float*)d_in[0];
    const float* x    = (const float*)d_in[1];
    const int*   ei   = (const int*)d_in[2];
    const float* We1  = (const float*)d_in[3];
    const float* be1  = (const float*)d_in[4];
    const float* We2  = (const float*)d_in[5];
    const float* be2  = (const float*)d_in[6];
    const float* ln_g = (const float*)d_in[7];
    const float* ln_b = (const float*)d_in[8];
    const float* Wh1  = (const float*)d_in[9];
    const float* bh1  = (const float*)d_in[10];
    const float* Wh2  = (const float*)d_in[11];
    const float* bh2  = (const float*)d_in[12];
    const float* Wx   = (const float*)d_in[13];
    const float* bx   = (const float*)d_in[14];
    const float* Wg   = (const float*)d_in[15];
    const float* bg   = (const float*)d_in[16];

    const int E = in_sizes[2] / 2;
    const int N = in_sizes[0] / DF;
    const int* src = ei;
    const int* dst = ei + E;

    // ---- workspace carve (16B aligned regions) ----
    char* base = (char*)d_ws;
    size_t o = 0;
    auto carve = [&](size_t bytes) -> void* {
        void* r = base + o;
        o = (o + bytes + 15) & ~(size_t)15;
        return r;
    };
    float* agg_h = (float*)carve((size_t)N * HID * 4);
    float* agg_x = (float*)carve((size_t)N * 3 * 4);
    float* Wt1   = (float*)carve(257 * 64 * 4);
    float* Wt2   = (float*)carve(64 * 64 * 4);
    float* Wht1  = (float*)carve(192 * 64 * 4);
    float* Wht2  = (float*)carve(64 * 128 * 4);
    int*   cnt   = (int*)carve((size_t)N * 4);
    int*   off   = (int*)carve(((size_t)N + 1) * 4);
    int*   bsum  = (int*)carve(256 * 4);
    int*   bofs  = (int*)carve(256 * 4);
    int*   dcnt  = (int*)carve(64 * 4);
    int*   dofs  = (int*)carve(64 * 4);
    int*   dnr   = (int*)carve((size_t)N * 4);
    int*   nodeorder = (int*)carve((size_t)N * 4);
    int*   rank  = (int*)carve((size_t)E * 4);
    int*   csr_src = (int*)carve((size_t)E * 4);
    size_t need_full = o;

    // Ps/Pd live in d_out (N*128 <= out_size N*131); d_out is fully
    // overwritten by node_kernel afterwards.
    float* Ps = (float*)d_out;
    float* Pd = Ps + (size_t)N * HID;

    const int gE  = (E + 255) / 256;
    const int Nb  = (N + 1023) / 1024;
    const int gN64 = (N + 63) / 64;

    hipMemsetAsync(cnt, 0, (size_t)N * 4, stream);
    prep_weights<<<(41024 + 255) / 256, 256, 0, stream>>>(We1, We2, Wh1, Wh2,
                                                          Wt1, Wt2, Wht1, Wht2);
    node_pre<<<gN64, 256, 0, stream>>>(h, Wt1, Ps, Pd, N);

    if (ws_size >= need_full) {
        // ---- CSR build ----
        hipMemsetAsync(dcnt, 0, 64 * 4, stream);
        count_kernel<<<gE, 256, 0, stream>>>(dst, cnt, rank, E);
        scan1<<<Nb, 1024, 0, stream>>>(cnt, off, bsum, N);
        scan2<<<1, 64, 0, stream>>>(bsum, bofs, Nb);
        scan3<<<(N + 256) / 256, 256, 0, stream>>>(off, bofs, N, E);
        scatter_src<<<gE, 256, 0, stream>>>(dst, src, rank, off, csr_src, E);
        deghist<<<(N + 255) / 256, 256, 0, stream>>>(cnt, dcnt, dnr, N);
        degscan<<<1, 64, 0, stream>>>(dcnt, dofs);
        degscatter<<<(N + 255) / 256, 256, 0, stream>>>(cnt, dnr, dofs, nodeorder, N);
        // ---- fused gather (no atomics), 8 lanes per node, LDS acc ----
        gather_kernel<<<((size_t)N * GS + 255) / 256, 256, 0, stream>>>(
            csr_src, off, nodeorder, x, Ps, Pd, Wt1, Wt2, be1, be2,
            ln_g, ln_b, Wx, bx, Wg, bg, agg_h, agg_x, N);
    } else {
        // ---- fallback: atomic aggregation ----
        hipMemsetAsync(agg_h, 0, (size_t)N * 67 * 4, stream);
        count_kernel<<<gE, 256, 0, stream>>>(dst, cnt, nullptr, E);
        edge_kernel_atomic<<<gE, 256, 0, stream>>>(src, dst, x, Ps, Pd, Wt1, Wt2,
                                                   be1, be2, ln_g, ln_b, Wx, bx,
                                                   Wg, bg, agg_h, agg_x, E);
    }

    node_kernel<<<gN64, 256, 0, stream>>>(h, x, agg_h, agg_x, cnt,
                                          Wht1, Wht2, bh1, bh2, (float*)d_out, N);
}

// Round 5
// 959.551 us; speedup vs baseline: 1.2139x; 1.2139x over previous
//
#include <hip/hip_runtime.h>
#include <math.h>

#define HID 64
#define DF  128
#define GS  8   // edge-slice lanes per node in gather

__device__ __forceinline__ float silu_f(float v) {
    return v / (1.0f + __expf(-v));
}

// ---------------------------------------------------------------------------
// Weight transposes: [k][f]-major so unrolled per-lane loops read weights at
// wave-uniform consecutive addresses (s_load batches).
// ---------------------------------------------------------------------------
__global__ void prep_weights(const float* __restrict__ We1, const float* __restrict__ We2,
                             const float* __restrict__ Wh1, const float* __restrict__ Wh2,
                             float* __restrict__ Wt1, float* __restrict__ Wt2,
                             float* __restrict__ Wht1, float* __restrict__ Wht2) {
    int i = blockIdx.x * 256 + threadIdx.x;
    if (i < 257 * 64) {
        int k = i >> 6, f = i & 63;
        Wt1[i] = We1[f * 257 + k];
        return;
    }
    int j = i - 257 * 64;
    if (j < 64 * 64) {
        int k = j >> 6, f = j & 63;
        Wt2[j] = We2[f * 64 + k];
        return;
    }
    j -= 64 * 64;
    if (j < 192 * 64) {
        int k = j >> 6, f = j & 63;
        Wht1[j] = Wh1[f * 192 + k];
        return;
    }
    j -= 192 * 64;
    if (j < 64 * 128) {
        int f = j >> 7, c = j & 127;
        Wht2[j] = Wh2[c * 64 + f];
        return;
    }
}

// ---------------------------------------------------------------------------
// CSR build
// ---------------------------------------------------------------------------
__global__ __launch_bounds__(256) void count_kernel(const int* __restrict__ dst,
                                                    int* __restrict__ cnt,
                                                    int* __restrict__ rank, int E) {
    int e = blockIdx.x * 256 + threadIdx.x;
    if (e >= E) return;
    int r = atomicAdd(&cnt[dst[e]], 1);
    if (rank) rank[e] = r;
}

__global__ __launch_bounds__(1024) void scan1(const int* __restrict__ cnt,
                                              int* __restrict__ off,
                                              int* __restrict__ bsum, int N) {
    __shared__ int sm[1024];
    int tid = threadIdx.x;
    int i = blockIdx.x * 1024 + tid;
    int v = (i < N) ? cnt[i] : 0;
    sm[tid] = v;
    __syncthreads();
    for (int ofs = 1; ofs < 1024; ofs <<= 1) {
        int t = (tid >= ofs) ? sm[tid - ofs] : 0;
        __syncthreads();
        sm[tid] += t;
        __syncthreads();
    }
    if (i < N) off[i] = sm[tid] - v;
    if (tid == 1023) bsum[blockIdx.x] = sm[1023];
}

__global__ void scan2(const int* __restrict__ bsum, int* __restrict__ bofs, int Nb) {
    if (threadIdx.x == 0) {
        int s = 0;
        for (int b = 0; b < Nb; ++b) { bofs[b] = s; s += bsum[b]; }
    }
}

__global__ __launch_bounds__(256) void scan3(int* __restrict__ off,
                                             const int* __restrict__ bofs,
                                             int N, int E) {
    int i = blockIdx.x * 256 + threadIdx.x;
    if (i > N) return;
    if (i == N) off[N] = E;
    else off[i] += bofs[i >> 10];
}

__global__ __launch_bounds__(256) void deghist(const int* __restrict__ cnt,
                                               int* __restrict__ dcnt,
                                               int* __restrict__ dnr, int N) {
    int n = blockIdx.x * 256 + threadIdx.x;
    if (n >= N) return;
    int b = min(cnt[n], 63);
    dnr[n] = atomicAdd(&dcnt[b], 1);
}

__global__ void degscan(const int* __restrict__ dcnt, int* __restrict__ dofs) {
    if (threadIdx.x == 0) {
        int s = 0;
        for (int b = 0; b < 64; ++b) { dofs[b] = s; s += dcnt[b]; }
    }
}

__global__ __launch_bounds__(256) void degscatter(const int* __restrict__ cnt,
                                                  const int* __restrict__ dnr,
                                                  const int* __restrict__ dofs,
                                                  int* __restrict__ nodeorder, int N) {
    int n = blockIdx.x * 256 + threadIdx.x;
    if (n >= N) return;
    int b = min(cnt[n], 63);
    nodeorder[dofs[b] + dnr[n]] = n;
}

// csr_src[off[dst[e]] + rank[e]] = src[e]
__global__ __launch_bounds__(256) void scatter_src(const int* __restrict__ dst,
                                                   const int* __restrict__ srcI,
                                                   const int* __restrict__ rank,
                                                   const int* __restrict__ off,
                                                   int* __restrict__ csr_src, int E) {
    int e = blockIdx.x * 256 + threadIdx.x;
    if (e >= E) return;
    csr_src[off[dst[e]] + rank[e]] = srcI[e];
}

// ---------------------------------------------------------------------------
// node_pre (wave-feature-split): 4 waves over 64 nodes; wave w does 16 feats.
// ---------------------------------------------------------------------------
__global__ __launch_bounds__(256) void node_pre(const float* __restrict__ h,
                                                const float* __restrict__ Wt1,
                                                float* __restrict__ Ps,
                                                float* __restrict__ Pd, int N) {
    int lane = threadIdx.x & 63;
    int w = __builtin_amdgcn_readfirstlane(threadIdx.x >> 6);
    int n = blockIdx.x * 64 + lane;
    if (n >= N) return;
    int f0 = w * 16;
    float accS[16], accD[16];
#pragma unroll
    for (int j = 0; j < 16; ++j) { accS[j] = 0.f; accD[j] = 0.f; }
    const float4* row = (const float4*)(h + (size_t)n * DF);
    for (int k4 = 0; k4 < DF / 4; ++k4) {
        float4 v = row[k4];
        float hv4[4] = {v.x, v.y, v.z, v.w};
#pragma unroll
        for (int jj = 0; jj < 4; ++jj) {
            int k = k4 * 4 + jj;
            float hv = hv4[jj];
#pragma unroll
            for (int j = 0; j < 16; ++j) {
                accS[j] = fmaf(hv, Wt1[k * HID + f0 + j], accS[j]);
                accD[j] = fmaf(hv, Wt1[(DF + k) * HID + f0 + j], accD[j]);
            }
        }
    }
    float4* ps = (float4*)(Ps + (size_t)n * HID + f0);
    float4* pd = (float4*)(Pd + (size_t)n * HID + f0);
#pragma unroll
    for (int j4 = 0; j4 < 4; ++j4) {
        ps[j4] = make_float4(accS[4 * j4], accS[4 * j4 + 1], accS[4 * j4 + 2], accS[4 * j4 + 3]);
        pd[j4] = make_float4(accD[4 * j4], accD[4 * j4 + 1], accD[4 * j4 + 2], accD[4 * j4 + 3]);
    }
}

// ---------------------------------------------------------------------------
// Gather: GS=8 lanes per dst node; each lane recomputes the edge MLP for
// every-GS'th edge; acc[64] and m[64] live in VGPRs. Plain launch_bounds(256):
// allocator picks ~180 VGPR (round-2 evidence: zero spill traffic at 180).
// 8-lane shfl_xor tree combines partial aggregates. No atomics, no LDS.
// ---------------------------------------------------------------------------
__global__ __launch_bounds__(256) void gather_kernel(
    const int* __restrict__ csr_src, const int* __restrict__ off,
    const int* __restrict__ nodeorder, const float* __restrict__ x,
    const float* __restrict__ Ps, const float* __restrict__ Pd,
    const float* __restrict__ Wt1, const float* __restrict__ Wt2,
    const float* __restrict__ be1, const float* __restrict__ be2,
    const float* __restrict__ ln_g, const float* __restrict__ ln_b,
    const float* __restrict__ Wx, const float* __restrict__ bx,
    const float* __restrict__ Wg, const float* __restrict__ bg,
    float* __restrict__ agg_h, float* __restrict__ agg_x, int N) {
    int gid = blockIdx.x * 256 + threadIdx.x;
    int slot = gid >> 3, sub = gid & (GS - 1);
    if (slot >= N) return;   // whole 8-lane group uniform -> safe
    int n = nodeorder[slot];
    int beg = off[n], end = off[n + 1];

    float xd0 = x[n * 3], xd1 = x[n * 3 + 1], xd2 = x[n * 3 + 2];
    const float* colW = Wt1 + 256 * HID;  // We1[:,256] (d_sq column)
    const float4* pd = (const float4*)(Pd + (size_t)n * HID);

    float acc[HID];
#pragma unroll
    for (int f = 0; f < HID; ++f) acc[f] = 0.f;
    float ax0 = 0.f, ax1 = 0.f, ax2 = 0.f;

    for (int i = beg + sub; i < end; i += GS) {
        int s = csr_src[i];
        float r0 = x[s * 3] - xd0, r1 = x[s * 3 + 1] - xd1, r2 = x[s * 3 + 2] - xd2;
        float dsq = r0 * r0 + r1 * r1 + r2 * r2;
        float inv = 1.0f / (sqrtf(dsq) + 1e-8f);
        float rn0 = r0 * inv, rn1 = r1 * inv, rn2 = r2 * inv;

        float m[HID];
#pragma unroll
        for (int f = 0; f < HID; ++f) m[f] = be2[f];

        const float4* ps = (const float4*)(Ps + (size_t)s * HID);
#pragma unroll
        for (int k4 = 0; k4 < HID / 4; ++k4) {
            float4 a = ps[k4];
            float4 b = pd[k4];
            float av[4] = {a.x, a.y, a.z, a.w};
            float bv[4] = {b.x, b.y, b.z, b.w};
#pragma unroll
            for (int j = 0; j < 4; ++j) {
                int k = 4 * k4 + j;
                float zk = silu_f(av[j] + bv[j] + be1[k] + dsq * colW[k]);
#pragma unroll
                for (int f = 0; f < HID; ++f) m[f] = fmaf(zk, Wt2[k * HID + f], m[f]);
            }
        }
#pragma unroll
        for (int f = 0; f < HID; ++f) m[f] = silu_f(m[f]);

        // LayerNorm
        float mu = 0.f;
#pragma unroll
        for (int f = 0; f < HID; ++f) mu += m[f];
        mu *= (1.0f / HID);
        float var = 0.f;
#pragma unroll
        for (int f = 0; f < HID; ++f) {
            float t = m[f] - mu;
            var = fmaf(t, t, var);
        }
        var *= (1.0f / HID);
        float rstd = 1.0f / sqrtf(var + 1e-5f);
#pragma unroll
        for (int f = 0; f < HID; ++f) m[f] = (m[f] - mu) * rstd * ln_g[f] + ln_b[f];

        // gates
        float dotg = 0.f, dotx = 0.f;
#pragma unroll
        for (int f = 0; f < HID; ++f) {
            dotg = fmaf(m[f], Wg[f], dotg);
            dotx = fmaf(m[f], Wx[f], dotx);
        }
        float alpha = 1.0f / (1.0f + __expf(-(dotg + bg[0])));
        float ta = __expf(2.0f * fmaf(alpha, dotx, bx[0]));
        float cw = 1.0f - 2.0f / (ta + 1.0f);

#pragma unroll
        for (int f = 0; f < HID; ++f) acc[f] = fmaf(m[f], alpha, acc[f]);
        ax0 = fmaf(rn0, cw, ax0);
        ax1 = fmaf(rn1, cw, ax1);
        ax2 = fmaf(rn2, cw, ax2);
    }

    // combine the GS partial aggregates (8-lane groups are wave-aligned)
#pragma unroll
    for (int d = 1; d < GS; d <<= 1) {
#pragma unroll
        for (int f = 0; f < HID; ++f) acc[f] += __shfl_xor(acc[f], d, 64);
        ax0 += __shfl_xor(ax0, d, 64);
        ax1 += __shfl_xor(ax1, d, 64);
        ax2 += __shfl_xor(ax2, d, 64);
    }

    if (sub == 0) {
        float4* ah = (float4*)(agg_h + (size_t)n * HID);
#pragma unroll
        for (int f4 = 0; f4 < HID / 4; ++f4)
            ah[f4] = make_float4(acc[4 * f4], acc[4 * f4 + 1], acc[4 * f4 + 2], acc[4 * f4 + 3]);
        agg_x[n * 3 + 0] = ax0;
        agg_x[n * 3 + 1] = ax1;
        agg_x[n * 3 + 2] = ax2;
    }
}

// ---------------------------------------------------------------------------
// Fallback edge kernel (atomic aggregation) — only if ws too small for CSR.
// ---------------------------------------------------------------------------
__global__ __launch_bounds__(256) void edge_kernel_atomic(
    const int* __restrict__ src, const int* __restrict__ dst,
    const float* __restrict__ x,
    const float* __restrict__ Ps, const float* __restrict__ Pd,
    const float* __restrict__ Wt1, const float* __restrict__ Wt2,
    const float* __restrict__ be1, const float* __restrict__ be2,
    const float* __restrict__ ln_g, const float* __restrict__ ln_b,
    const float* __restrict__ Wx, const float* __restrict__ bx,
    const float* __restrict__ Wg, const float* __restrict__ bg,
    float* __restrict__ agg_h, float* __restrict__ agg_x, int E) {
    int e = blockIdx.x * 256 + threadIdx.x;
    if (e >= E) return;
    int s = src[e], d = dst[e];
    float r0 = x[s * 3] - x[d * 3], r1 = x[s * 3 + 1] - x[d * 3 + 1], r2 = x[s * 3 + 2] - x[d * 3 + 2];
    float dsq = r0 * r0 + r1 * r1 + r2 * r2;
    float inv = 1.0f / (sqrtf(dsq) + 1e-8f);
    float rn0 = r0 * inv, rn1 = r1 * inv, rn2 = r2 * inv;
    float z[HID];
    const float4* ps = (const float4*)(Ps + (size_t)s * HID);
    const float4* pd = (const float4*)(Pd + (size_t)d * HID);
    const float* colW = Wt1 + 256 * HID;
#pragma unroll
    for (int f4 = 0; f4 < HID / 4; ++f4) {
        float4 a = ps[f4];
        float4 b = pd[f4];
        float av[4] = {a.x, a.y, a.z, a.w};
        float bv[4] = {b.x, b.y, b.z, b.w};
#pragma unroll
        for (int j = 0; j < 4; ++j) {
            int f = 4 * f4 + j;
            z[f] = silu_f(av[j] + bv[j] + be1[f] + dsq * colW[f]);
        }
    }
    float m[HID];
#pragma unroll
    for (int f = 0; f < HID; ++f) m[f] = be2[f];
#pragma unroll
    for (int k = 0; k < HID; ++k) {
        float zv = z[k];
#pragma unroll
        for (int f = 0; f < HID; ++f) m[f] = fmaf(zv, Wt2[k * HID + f], m[f]);
    }
#pragma unroll
    for (int f = 0; f < HID; ++f) m[f] = silu_f(m[f]);
    float mu = 0.f;
#pragma unroll
    for (int f = 0; f < HID; ++f) mu += m[f];
    mu *= (1.0f / HID);
    float var = 0.f;
#pragma unroll
    for (int f = 0; f < HID; ++f) {
        float t = m[f] - mu;
        var = fmaf(t, t, var);
    }
    var *= (1.0f / HID);
    float rstd = 1.0f / sqrtf(var + 1e-5f);
#pragma unroll
    for (int f = 0; f < HID; ++f) m[f] = (m[f] - mu) * rstd * ln_g[f] + ln_b[f];
    float dotg = 0.f, dotx = 0.f;
#pragma unroll
    for (int f = 0; f < HID; ++f) {
        dotg = fmaf(m[f], Wg[f], dotg);
        dotx = fmaf(m[f], Wx[f], dotx);
    }
    float alpha = 1.0f / (1.0f + __expf(-(dotg + bg[0])));
    float ta = __expf(2.0f * fmaf(alpha, dotx, bx[0]));
    float cw = 1.0f - 2.0f / (ta + 1.0f);
    float* ah = agg_h + (size_t)d * HID;
#pragma unroll
    for (int f = 0; f < HID; ++f) atomicAdd(&ah[f], m[f] * alpha);
    atomicAdd(&agg_x[d * 3 + 0], rn0 * cw);
    atomicAdd(&agg_x[d * 3 + 1], rn1 * cw);
    atomicAdd(&agg_x[d * 3 + 2], rn2 * cw);
}

// ---------------------------------------------------------------------------
// node_kernel (wave-feature-split, LDS hh exchange)
// ---------------------------------------------------------------------------
__global__ __launch_bounds__(256) void node_kernel(
    const float* __restrict__ h, const float* __restrict__ x,
    const float* __restrict__ agg_h, const float* __restrict__ agg_x,
    const int* __restrict__ degI,
    const float* __restrict__ Wht1, const float* __restrict__ Wht2,
    const float* __restrict__ bh1, const float* __restrict__ bh2,
    float* __restrict__ out, int N) {
    __shared__ float hh[64 * 65];
    int lane = threadIdx.x & 63;
    int w = __builtin_amdgcn_readfirstlane(threadIdx.x >> 6);
    int n = blockIdx.x * 64 + lane;

    if (n < N) {
        int f0 = w * 16;
        float t[16];
#pragma unroll
        for (int j = 0; j < 16; ++j) t[j] = bh1[f0 + j];
        const float4* rowH = (const float4*)(h + (size_t)n * DF);
        for (int k4 = 0; k4 < DF / 4; ++k4) {
            float4 v = rowH[k4];
            float hv4[4] = {v.x, v.y, v.z, v.w};
#pragma unroll
            for (int jj = 0; jj < 4; ++jj) {
                int k = k4 * 4 + jj;
                float hv = hv4[jj];
#pragma unroll
                for (int j = 0; j < 16; ++j) t[j] = fmaf(hv, Wht1[k * HID + f0 + j], t[j]);
            }
        }
        const float4* rowA = (const float4*)(agg_h + (size_t)n * HID);
        for (int k4 = 0; k4 < HID / 4; ++k4) {
            float4 v = rowA[k4];
            float hv4[4] = {v.x, v.y, v.z, v.w};
#pragma unroll
            for (int jj = 0; jj < 4; ++jj) {
                int k = DF + k4 * 4 + jj;
                float hv = hv4[jj];
#pragma unroll
                for (int j = 0; j < 16; ++j) t[j] = fmaf(hv, Wht1[k * HID + f0 + j], t[j]);
            }
        }
#pragma unroll
        for (int j = 0; j < 16; ++j) hh[lane * 65 + f0 + j] = silu_f(t[j]);
    }
    __syncthreads();
    if (n >= N) return;

    int c0 = w * 32;
    float o[32];
#pragma unroll
    for (int j = 0; j < 32; ++j) o[j] = bh2[c0 + j];
    for (int k = 0; k < HID; ++k) {
        float hv = hh[lane * 65 + k];
#pragma unroll
        for (int j = 0; j < 32; ++j) o[j] = fmaf(hv, Wht2[k * DF + c0 + j], o[j]);
    }
    float* oh = out + (size_t)n * DF + c0;
    const float* hrow = h + (size_t)n * DF + c0;
#pragma unroll
    for (int j4 = 0; j4 < 8; ++j4) {
        float4 hv = ((const float4*)hrow)[j4];
        float4 r;
        r.x = hv.x + o[4 * j4];
        r.y = hv.y + o[4 * j4 + 1];
        r.z = hv.z + o[4 * j4 + 2];
        r.w = hv.w + o[4 * j4 + 3];
        ((float4*)oh)[j4] = r;
    }
    if (w == 0) {
        float dv = (float)degI[n];
        float invd = 1.0f / fmaxf(dv, 1.0f);
        float* ox = out + (size_t)N * DF + (size_t)n * 3;
        ox[0] = x[n * 3 + 0] + agg_x[n * 3 + 0] * invd;
        ox[1] = x[n * 3 + 1] + agg_x[n * 3 + 1] * invd;
        ox[2] = x[n * 3 + 2] + agg_x[n * 3 + 2] * invd;
    }
}

extern "C" void kernel_launch(void* const* d_in, const int* in_sizes, int n_in,
                              void* d_out, int out_size, void* d_ws, size_t ws_size,
                              hipStream_t stream) {
    const float* h    = (const float*)d_in[0];
    const float* x    = (const float*)d_in[1];
    const int*   ei   = (const int*)d_in[2];
    const float* We1  = (const float*)d_in[3];
    const float* be1  = (const float*)d_in[4];
    const float* We2  = (const float*)d_in[5];
    const float* be2  = (const float*)d_in[6];
    const float* ln_g = (const float*)d_in[7];
    const float* ln_b = (const float*)d_in[8];
    const float* Wh1  = (const float*)d_in[9];
    const float* bh1  = (const float*)d_in[10];
    const float* Wh2  = (const float*)d_in[11];
    const float* bh2  = (const float*)d_in[12];
    const float* Wx   = (const float*)d_in[13];
    const float* bx   = (const float*)d_in[14];
    const float* Wg   = (const float*)d_in[15];
    const float* bg   = (const float*)d_in[16];

    const int E = in_sizes[2] / 2;
    const int N = in_sizes[0] / DF;
    const int* src = ei;
    const int* dst = ei + E;

    // ---- workspace carve (16B aligned regions) ----
    char* base = (char*)d_ws;
    size_t o = 0;
    auto carve = [&](size_t bytes) -> void* {
        void* r = base + o;
        o = (o + bytes + 15) & ~(size_t)15;
        return r;
    };
    float* agg_h = (float*)carve((size_t)N * HID * 4);
    float* agg_x = (float*)carve((size_t)N * 3 * 4);
    float* Wt1   = (float*)carve(257 * 64 * 4);
    float* Wt2   = (float*)carve(64 * 64 * 4);
    float* Wht1  = (float*)carve(192 * 64 * 4);
    float* Wht2  = (float*)carve(64 * 128 * 4);
    int*   cnt   = (int*)carve((size_t)N * 4);
    int*   off   = (int*)carve(((size_t)N + 1) * 4);
    int*   bsum  = (int*)carve(256 * 4);
    int*   bofs  = (int*)carve(256 * 4);
    int*   dcnt  = (int*)carve(64 * 4);
    int*   dofs  = (int*)carve(64 * 4);
    int*   dnr   = (int*)carve((size_t)N * 4);
    int*   nodeorder = (int*)carve((size_t)N * 4);
    int*   rank  = (int*)carve((size_t)E * 4);
    int*   csr_src = (int*)carve((size_t)E * 4);
    size_t need_full = o;

    // Ps/Pd live in d_out (N*128 <= out_size N*131); d_out is fully
    // overwritten by node_kernel afterwards.
    float* Ps = (float*)d_out;
    float* Pd = Ps + (size_t)N * HID;

    const int gE  = (E + 255) / 256;
    const int Nb  = (N + 1023) / 1024;
    const int gN64 = (N + 63) / 64;

    hipMemsetAsync(cnt, 0, (size_t)N * 4, stream);
    prep_weights<<<(41024 + 255) / 256, 256, 0, stream>>>(We1, We2, Wh1, Wh2,
                                                          Wt1, Wt2, Wht1, Wht2);
    node_pre<<<gN64, 256, 0, stream>>>(h, Wt1, Ps, Pd, N);

    if (ws_size >= need_full) {
        // ---- CSR build ----
        hipMemsetAsync(dcnt, 0, 64 * 4, stream);
        count_kernel<<<gE, 256, 0, stream>>>(dst, cnt, rank, E);
        scan1<<<Nb, 1024, 0, stream>>>(cnt, off, bsum, N);
        scan2<<<1, 64, 0, stream>>>(bsum, bofs, Nb);
        scan3<<<(N + 256) / 256, 256, 0, stream>>>(off, bofs, N, E);
        scatter_src<<<gE, 256, 0, stream>>>(dst, src, rank, off, csr_src, E);
        deghist<<<(N + 255) / 256, 256, 0, stream>>>(cnt, dcnt, dnr, N);
        degscan<<<1, 64, 0, stream>>>(dcnt, dofs);
        degscatter<<<(N + 255) / 256, 256, 0, stream>>>(cnt, dnr, dofs, nodeorder, N);
        // ---- fused gather (no atomics), 8 lanes per node, regs only ----
        gather_kernel<<<((size_t)N * GS + 255) / 256, 256, 0, stream>>>(
            csr_src, off, nodeorder, x, Ps, Pd, Wt1, Wt2, be1, be2,
            ln_g, ln_b, Wx, bx, Wg, bg, agg_h, agg_x, N);
    } else {
        // ---- fallback: atomic aggregation ----
        hipMemsetAsync(agg_h, 0, (size_t)N * 67 * 4, stream);
        count_kernel<<<gE, 256, 0, stream>>>(dst, cnt, nullptr, E);
        edge_kernel_atomic<<<gE, 256, 0, stream>>>(src, dst, x, Ps, Pd, Wt1, Wt2,
                                                   be1, be2, ln_g, ln_b, Wx, bx,
                                                   Wg, bg, agg_h, agg_x, E);
    }

    node_kernel<<<gN64, 256, 0, stream>>>(h, x, agg_h, agg_x, cnt,
                                          Wht1, Wht2, bh1, bh2, (float*)d_out, N);
}

// Round 6
// 731.398 us; speedup vs baseline: 1.5926x; 1.3119x over previous
//
#include <hip/hip_runtime.h>
#include <math.h>

#define HID 64
#define DF  128

__device__ __forceinline__ float silu_f(float v) {
    return v / (1.0f + __expf(-v));
}

// wave-wide (64-lane) sum reduction
__device__ __forceinline__ float wredsum(float v) {
#pragma unroll
    for (int d = 1; d < 64; d <<= 1) v += __shfl_xor(v, d, 64);
    return v;
}

// ---------------------------------------------------------------------------
// Weight transposes: [k][f]-major layouts.
// ---------------------------------------------------------------------------
__global__ void prep_weights(const float* __restrict__ We1, const float* __restrict__ We2,
                             const float* __restrict__ Wh1, const float* __restrict__ Wh2,
                             float* __restrict__ Wt1, float* __restrict__ Wt2,
                             float* __restrict__ Wht1, float* __restrict__ Wht2) {
    int i = blockIdx.x * 256 + threadIdx.x;
    if (i < 257 * 64) {
        int k = i >> 6, f = i & 63;
        Wt1[i] = We1[f * 257 + k];
        return;
    }
    int j = i - 257 * 64;
    if (j < 64 * 64) {
        int k = j >> 6, f = j & 63;
        Wt2[j] = We2[f * 64 + k];
        return;
    }
    j -= 64 * 64;
    if (j < 192 * 64) {
        int k = j >> 6, f = j & 63;
        Wht1[j] = Wh1[f * 192 + k];
        return;
    }
    j -= 192 * 64;
    if (j < 64 * 128) {
        int f = j >> 7, c = j & 127;
        Wht2[j] = Wh2[c * 64 + f];
        return;
    }
}

// ---------------------------------------------------------------------------
// CSR build
// ---------------------------------------------------------------------------
__global__ __launch_bounds__(256) void count_kernel(const int* __restrict__ dst,
                                                    int* __restrict__ cnt,
                                                    int* __restrict__ rank, int E) {
    int e = blockIdx.x * 256 + threadIdx.x;
    if (e >= E) return;
    int r = atomicAdd(&cnt[dst[e]], 1);
    if (rank) rank[e] = r;
}

__global__ __launch_bounds__(1024) void scan1(const int* __restrict__ cnt,
                                              int* __restrict__ off,
                                              int* __restrict__ bsum, int N) {
    __shared__ int sm[1024];
    int tid = threadIdx.x;
    int i = blockIdx.x * 1024 + tid;
    int v = (i < N) ? cnt[i] : 0;
    sm[tid] = v;
    __syncthreads();
    for (int ofs = 1; ofs < 1024; ofs <<= 1) {
        int t = (tid >= ofs) ? sm[tid - ofs] : 0;
        __syncthreads();
        sm[tid] += t;
        __syncthreads();
    }
    if (i < N) off[i] = sm[tid] - v;
    if (tid == 1023) bsum[blockIdx.x] = sm[1023];
}

__global__ void scan2(const int* __restrict__ bsum, int* __restrict__ bofs, int Nb) {
    if (threadIdx.x == 0) {
        int s = 0;
        for (int b = 0; b < Nb; ++b) { bofs[b] = s; s += bsum[b]; }
    }
}

__global__ __launch_bounds__(256) void scan3(int* __restrict__ off,
                                             const int* __restrict__ bofs,
                                             int N, int E) {
    int i = blockIdx.x * 256 + threadIdx.x;
    if (i > N) return;
    if (i == N) off[N] = E;
    else off[i] += bofs[i >> 10];
}

__global__ __launch_bounds__(256) void deghist(const int* __restrict__ cnt,
                                               int* __restrict__ dcnt,
                                               int* __restrict__ dnr, int N) {
    int n = blockIdx.x * 256 + threadIdx.x;
    if (n >= N) return;
    int b = min(cnt[n], 63);
    dnr[n] = atomicAdd(&dcnt[b], 1);
}

__global__ void degscan(const int* __restrict__ dcnt, int* __restrict__ dofs) {
    if (threadIdx.x == 0) {
        int s = 0;
        for (int b = 0; b < 64; ++b) { dofs[b] = s; s += dcnt[b]; }
    }
}

__global__ __launch_bounds__(256) void degscatter(const int* __restrict__ cnt,
                                                  const int* __restrict__ dnr,
                                                  const int* __restrict__ dofs,
                                                  int* __restrict__ nodeorder, int N) {
    int n = blockIdx.x * 256 + threadIdx.x;
    if (n >= N) return;
    int b = min(cnt[n], 63);
    nodeorder[dofs[b] + dnr[n]] = n;
}

// csr_src[off[dst[e]] + rank[e]] = src[e]
__global__ __launch_bounds__(256) void scatter_src(const int* __restrict__ dst,
                                                   const int* __restrict__ srcI,
                                                   const int* __restrict__ rank,
                                                   const int* __restrict__ off,
                                                   int* __restrict__ csr_src, int E) {
    int e = blockIdx.x * 256 + threadIdx.x;
    if (e >= E) return;
    csr_src[off[dst[e]] + rank[e]] = srcI[e];
}

// ---------------------------------------------------------------------------
// node_pre (wave-feature-split): 4 waves over 64 nodes; wave w does 16 feats.
// ---------------------------------------------------------------------------
__global__ __launch_bounds__(256) void node_pre(const float* __restrict__ h,
                                                const float* __restrict__ Wt1,
                                                float* __restrict__ Ps,
                                                float* __restrict__ Pd, int N) {
    int lane = threadIdx.x & 63;
    int w = __builtin_amdgcn_readfirstlane(threadIdx.x >> 6);
    int n = blockIdx.x * 64 + lane;
    if (n >= N) return;
    int f0 = w * 16;
    float accS[16], accD[16];
#pragma unroll
    for (int j = 0; j < 16; ++j) { accS[j] = 0.f; accD[j] = 0.f; }
    const float4* row = (const float4*)(h + (size_t)n * DF);
    for (int k4 = 0; k4 < DF / 4; ++k4) {
        float4 v = row[k4];
        float hv4[4] = {v.x, v.y, v.z, v.w};
#pragma unroll
        for (int jj = 0; jj < 4; ++jj) {
            int k = k4 * 4 + jj;
            float hv = hv4[jj];
#pragma unroll
            for (int j = 0; j < 16; ++j) {
                accS[j] = fmaf(hv, Wt1[k * HID + f0 + j], accS[j]);
                accD[j] = fmaf(hv, Wt1[(DF + k) * HID + f0 + j], accD[j]);
            }
        }
    }
    float4* ps = (float4*)(Ps + (size_t)n * HID + f0);
    float4* pd = (float4*)(Pd + (size_t)n * HID + f0);
#pragma unroll
    for (int j4 = 0; j4 < 4; ++j4) {
        ps[j4] = make_float4(accS[4 * j4], accS[4 * j4 + 1], accS[4 * j4 + 2], accS[4 * j4 + 3]);
        pd[j4] = make_float4(accD[4 * j4], accD[4 * j4 + 1], accD[4 * j4 + 2], accD[4 * j4 + 3]);
    }
}

// ---------------------------------------------------------------------------
// Gather v3: ONE WAVE per dst node, ONE FEATURE per lane.
//   lane f keeps We2 column f (64 floats) RESIDENT in VGPRs -> zero weight
//   re-streaming. Per edge: z_k computed one-per-lane (coalesced Ps row read),
//   broadcast via a 64-float LDS slot (uniform ds_read_b128, broadcast);
//   LN/gates via wave shfl_xor reductions; acc is 1 VGPR per lane.
// ---------------------------------------------------------------------------
__global__ __launch_bounds__(256) void gather_kernel(
    const int* __restrict__ csr_src, const int* __restrict__ off,
    const int* __restrict__ nodeorder, const float* __restrict__ x,
    const float* __restrict__ Ps, const float* __restrict__ Pd,
    const float* __restrict__ Wt1, const float* __restrict__ Wt2,
    const float* __restrict__ be1, const float* __restrict__ be2,
    const float* __restrict__ ln_g, const float* __restrict__ ln_b,
    const float* __restrict__ Wx, const float* __restrict__ bx,
    const float* __restrict__ Wg, const float* __restrict__ bg,
    float* __restrict__ agg_h, float* __restrict__ agg_x, int N) {
    __shared__ float smz[4][64];
    const int lane = threadIdx.x & 63;
    const int wslot = threadIdx.x >> 6;
    const int wid = blockIdx.x * 4 + wslot;
    if (wid >= N) return;
    const int n = nodeorder[wid];
    const int beg = off[n], end = off[n + 1];

    // resident per-lane constants (feature = lane)
    float w[64];
#pragma unroll
    for (int k = 0; k < 64; ++k) w[k] = Wt2[k * HID + lane];  // We2[lane][k]
    const float basef = Pd[(size_t)n * HID + lane] + be1[lane];
    const float colWf = Wt1[256 * HID + lane];   // We1[:,256] (d_sq column)
    const float be2f = be2[lane];
    const float gf = ln_g[lane], bf = ln_b[lane];
    const float wgf = Wg[lane], wxf = Wx[lane];
    const float bgs = bg[0], bxs = bx[0];
    const float xd0 = x[n * 3], xd1 = x[n * 3 + 1], xd2 = x[n * 3 + 2];

    float acc = 0.f, ax0 = 0.f, ax1 = 0.f, ax2 = 0.f;

    if (beg < end) {
        // software-pipelined: prefetch edge i+1's src/x/Ps during edge i
        int s = csr_src[beg];
        float xs0 = x[s * 3], xs1 = x[s * 3 + 1], xs2 = x[s * 3 + 2];
        float psv = Ps[(size_t)s * HID + lane];

        for (int i = beg; i < end; ++i) {
            int ip = (i + 1 < end) ? i + 1 : i;
            int s_nx = csr_src[ip];
            float xn0 = x[s_nx * 3], xn1 = x[s_nx * 3 + 1], xn2 = x[s_nx * 3 + 2];
            float psn = Ps[(size_t)s_nx * HID + lane];

            float r0 = xs0 - xd0, r1 = xs1 - xd1, r2 = xs2 - xd2;
            float dsq = r0 * r0 + r1 * r1 + r2 * r2;
            float inv = 1.0f / (sqrtf(dsq) + 1e-8f);

            float z = silu_f(psv + basef + dsq * colWf);
            smz[wslot][lane] = z;
            __builtin_amdgcn_wave_barrier();

            // m[lane] = be2 + sum_k z_k * We2[lane][k]  (4 partial chains)
            float m0 = be2f, m1 = 0.f, m2 = 0.f, m3 = 0.f;
#pragma unroll
            for (int k4 = 0; k4 < 16; ++k4) {
                float4 zc = *(const float4*)&smz[wslot][k4 * 4];
                m0 = fmaf(zc.x, w[4 * k4 + 0], m0);
                m1 = fmaf(zc.y, w[4 * k4 + 1], m1);
                m2 = fmaf(zc.z, w[4 * k4 + 2], m2);
                m3 = fmaf(zc.w, w[4 * k4 + 3], m3);
            }
            __builtin_amdgcn_wave_barrier();  // next iter's write stays after reads
            float m = silu_f((m0 + m1) + (m2 + m3));

            // LayerNorm across the wave (feature = lane)
            float mu = wredsum(m) * (1.0f / HID);
            float t = m - mu;
            float var = wredsum(t * t) * (1.0f / HID);
            float rstd = 1.0f / sqrtf(var + 1e-5f);
            float mn = fmaf(t * rstd, gf, bf);

            // gates (wave reductions; results uniform across lanes)
            float dg = wredsum(mn * wgf);
            float dx = wredsum(mn * wxf);
            float alpha = 1.0f / (1.0f + __expf(-(dg + bgs)));
            float ta = __expf(2.0f * fmaf(alpha, dx, bxs));
            float cw = 1.0f - 2.0f / (ta + 1.0f);

            acc = fmaf(mn, alpha, acc);
            float rc = inv * cw;
            ax0 = fmaf(r0, rc, ax0);
            ax1 = fmaf(r1, rc, ax1);
            ax2 = fmaf(r2, rc, ax2);

            xs0 = xn0; xs1 = xn1; xs2 = xn2; psv = psn;
        }
    }

    agg_h[(size_t)n * HID + lane] = acc;
    if (lane == 0) {
        agg_x[n * 3 + 0] = ax0;
        agg_x[n * 3 + 1] = ax1;
        agg_x[n * 3 + 2] = ax2;
    }
}

// ---------------------------------------------------------------------------
// Fallback edge kernel (atomic aggregation) — only if ws too small for CSR.
// ---------------------------------------------------------------------------
__global__ __launch_bounds__(256) void edge_kernel_atomic(
    const int* __restrict__ src, const int* __restrict__ dst,
    const float* __restrict__ x,
    const float* __restrict__ Ps, const float* __restrict__ Pd,
    const float* __restrict__ Wt1, const float* __restrict__ Wt2,
    const float* __restrict__ be1, const float* __restrict__ be2,
    const float* __restrict__ ln_g, const float* __restrict__ ln_b,
    const float* __restrict__ Wx, const float* __restrict__ bx,
    const float* __restrict__ Wg, const float* __restrict__ bg,
    float* __restrict__ agg_h, float* __restrict__ agg_x, int E) {
    int e = blockIdx.x * 256 + threadIdx.x;
    if (e >= E) return;
    int s = src[e], d = dst[e];
    float r0 = x[s * 3] - x[d * 3], r1 = x[s * 3 + 1] - x[d * 3 + 1], r2 = x[s * 3 + 2] - x[d * 3 + 2];
    float dsq = r0 * r0 + r1 * r1 + r2 * r2;
    float inv = 1.0f / (sqrtf(dsq) + 1e-8f);
    float rn0 = r0 * inv, rn1 = r1 * inv, rn2 = r2 * inv;
    float z[HID];
    const float4* ps = (const float4*)(Ps + (size_t)s * HID);
    const float4* pd = (const float4*)(Pd + (size_t)d * HID);
    const float* colW = Wt1 + 256 * HID;
#pragma unroll
    for (int f4 = 0; f4 < HID / 4; ++f4) {
        float4 a = ps[f4];
        float4 b = pd[f4];
        float av[4] = {a.x, a.y, a.z, a.w};
        float bv[4] = {b.x, b.y, b.z, b.w};
#pragma unroll
        for (int j = 0; j < 4; ++j) {
            int f = 4 * f4 + j;
            z[f] = silu_f(av[j] + bv[j] + be1[f] + dsq * colW[f]);
        }
    }
    float m[HID];
#pragma unroll
    for (int f = 0; f < HID; ++f) m[f] = be2[f];
#pragma unroll
    for (int k = 0; k < HID; ++k) {
        float zv = z[k];
#pragma unroll
        for (int f = 0; f < HID; ++f) m[f] = fmaf(zv, Wt2[k * HID + f], m[f]);
    }
#pragma unroll
    for (int f = 0; f < HID; ++f) m[f] = silu_f(m[f]);
    float mu = 0.f;
#pragma unroll
    for (int f = 0; f < HID; ++f) mu += m[f];
    mu *= (1.0f / HID);
    float var = 0.f;
#pragma unroll
    for (int f = 0; f < HID; ++f) {
        float t = m[f] - mu;
        var = fmaf(t, t, var);
    }
    var *= (1.0f / HID);
    float rstd = 1.0f / sqrtf(var + 1e-5f);
#pragma unroll
    for (int f = 0; f < HID; ++f) m[f] = (m[f] - mu) * rstd * ln_g[f] + ln_b[f];
    float dotg = 0.f, dotx = 0.f;
#pragma unroll
    for (int f = 0; f < HID; ++f) {
        dotg = fmaf(m[f], Wg[f], dotg);
        dotx = fmaf(m[f], Wx[f], dotx);
    }
    float alpha = 1.0f / (1.0f + __expf(-(dotg + bg[0])));
    float ta = __expf(2.0f * fmaf(alpha, dotx, bx[0]));
    float cw = 1.0f - 2.0f / (ta + 1.0f);
    float* ah = agg_h + (size_t)d * HID;
#pragma unroll
    for (int f = 0; f < HID; ++f) atomicAdd(&ah[f], m[f] * alpha);
    atomicAdd(&agg_x[d * 3 + 0], rn0 * cw);
    atomicAdd(&agg_x[d * 3 + 1], rn1 * cw);
    atomicAdd(&agg_x[d * 3 + 2], rn2 * cw);
}

// ---------------------------------------------------------------------------
// node_kernel (wave-feature-split, LDS hh exchange)
// ---------------------------------------------------------------------------
__global__ __launch_bounds__(256) void node_kernel(
    const float* __restrict__ h, const float* __restrict__ x,
    const float* __restrict__ agg_h, const float* __restrict__ agg_x,
    const int* __restrict__ degI,
    const float* __restrict__ Wht1, const float* __restrict__ Wht2,
    const float* __restrict__ bh1, const float* __restrict__ bh2,
    float* __restrict__ out, int N) {
    __shared__ float hh[64 * 65];
    int lane = threadIdx.x & 63;
    int w = __builtin_amdgcn_readfirstlane(threadIdx.x >> 6);
    int n = blockIdx.x * 64 + lane;

    if (n < N) {
        int f0 = w * 16;
        float t[16];
#pragma unroll
        for (int j = 0; j < 16; ++j) t[j] = bh1[f0 + j];
        const float4* rowH = (const float4*)(h + (size_t)n * DF);
        for (int k4 = 0; k4 < DF / 4; ++k4) {
            float4 v = rowH[k4];
            float hv4[4] = {v.x, v.y, v.z, v.w};
#pragma unroll
            for (int jj = 0; jj < 4; ++jj) {
                int k = k4 * 4 + jj;
                float hv = hv4[jj];
#pragma unroll
                for (int j = 0; j < 16; ++j) t[j] = fmaf(hv, Wht1[k * HID + f0 + j], t[j]);
            }
        }
        const float4* rowA = (const float4*)(agg_h + (size_t)n * HID);
        for (int k4 = 0; k4 < HID / 4; ++k4) {
            float4 v = rowA[k4];
            float hv4[4] = {v.x, v.y, v.z, v.w};
#pragma unroll
            for (int jj = 0; jj < 4; ++jj) {
                int k = DF + k4 * 4 + jj;
                float hv = hv4[jj];
#pragma unroll
                for (int j = 0; j < 16; ++j) t[j] = fmaf(hv, Wht1[k * HID + f0 + j], t[j]);
            }
        }
#pragma unroll
        for (int j = 0; j < 16; ++j) hh[lane * 65 + f0 + j] = silu_f(t[j]);
    }
    __syncthreads();
    if (n >= N) return;

    int c0 = w * 32;
    float o[32];
#pragma unroll
    for (int j = 0; j < 32; ++j) o[j] = bh2[c0 + j];
    for (int k = 0; k < HID; ++k) {
        float hv = hh[lane * 65 + k];
#pragma unroll
        for (int j = 0; j < 32; ++j) o[j] = fmaf(hv, Wht2[k * DF + c0 + j], o[j]);
    }
    float* oh = out + (size_t)n * DF + c0;
    const float* hrow = h + (size_t)n * DF + c0;
#pragma unroll
    for (int j4 = 0; j4 < 8; ++j4) {
        float4 hv = ((const float4*)hrow)[j4];
        float4 r;
        r.x = hv.x + o[4 * j4];
        r.y = hv.y + o[4 * j4 + 1];
        r.z = hv.z + o[4 * j4 + 2];
        r.w = hv.w + o[4 * j4 + 3];
        ((float4*)oh)[j4] = r;
    }
    if (w == 0) {
        float dv = (float)degI[n];
        float invd = 1.0f / fmaxf(dv, 1.0f);
        float* ox = out + (size_t)N * DF + (size_t)n * 3;
        ox[0] = x[n * 3 + 0] + agg_x[n * 3 + 0] * invd;
        ox[1] = x[n * 3 + 1] + agg_x[n * 3 + 1] * invd;
        ox[2] = x[n * 3 + 2] + agg_x[n * 3 + 2] * invd;
    }
}

extern "C" void kernel_launch(void* const* d_in, const int* in_sizes, int n_in,
                              void* d_out, int out_size, void* d_ws, size_t ws_size,
                              hipStream_t stream) {
    const float* h    = (const float*)d_in[0];
    const float* x    = (const float*)d_in[1];
    const int*   ei   = (const int*)d_in[2];
    const float* We1  = (const float*)d_in[3];
    const float* be1  = (const float*)d_in[4];
    const float* We2  = (const float*)d_in[5];
    const float* be2  = (const float*)d_in[6];
    const float* ln_g = (const float*)d_in[7];
    const float* ln_b = (const float*)d_in[8];
    const float* Wh1  = (const float*)d_in[9];
    const float* bh1  = (const float*)d_in[10];
    const float* Wh2  = (const float*)d_in[11];
    const float* bh2  = (const float*)d_in[12];
    const float* Wx   = (const float*)d_in[13];
    const float* bx   = (const float*)d_in[14];
    const float* Wg   = (const float*)d_in[15];
    const float* bg   = (const float*)d_in[16];

    const int E = in_sizes[2] / 2;
    const int N = in_sizes[0] / DF;
    const int* src = ei;
    const int* dst = ei + E;

    // ---- workspace carve (16B aligned regions) ----
    char* base = (char*)d_ws;
    size_t o = 0;
    auto carve = [&](size_t bytes) -> void* {
        void* r = base + o;
        o = (o + bytes + 15) & ~(size_t)15;
        return r;
    };
    float* agg_h = (float*)carve((size_t)N * HID * 4);
    float* agg_x = (float*)carve((size_t)N * 3 * 4);
    float* Wt1   = (float*)carve(257 * 64 * 4);
    float* Wt2   = (float*)carve(64 * 64 * 4);
    float* Wht1  = (float*)carve(192 * 64 * 4);
    float* Wht2  = (float*)carve(64 * 128 * 4);
    int*   cnt   = (int*)carve((size_t)N * 4);
    int*   off   = (int*)carve(((size_t)N + 1) * 4);
    int*   bsum  = (int*)carve(256 * 4);
    int*   bofs  = (int*)carve(256 * 4);
    int*   dcnt  = (int*)carve(64 * 4);
    int*   dofs  = (int*)carve(64 * 4);
    int*   dnr   = (int*)carve((size_t)N * 4);
    int*   nodeorder = (int*)carve((size_t)N * 4);
    int*   rank  = (int*)carve((size_t)E * 4);
    int*   csr_src = (int*)carve((size_t)E * 4);
    size_t need_full = o;

    // Ps/Pd live in d_out (N*128 <= out_size N*131); d_out is fully
    // overwritten by node_kernel afterwards.
    float* Ps = (float*)d_out;
    float* Pd = Ps + (size_t)N * HID;

    const int gE  = (E + 255) / 256;
    const int Nb  = (N + 1023) / 1024;
    const int gN64 = (N + 63) / 64;

    hipMemsetAsync(cnt, 0, (size_t)N * 4, stream);
    prep_weights<<<(41024 + 255) / 256, 256, 0, stream>>>(We1, We2, Wh1, Wh2,
                                                          Wt1, Wt2, Wht1, Wht2);
    node_pre<<<gN64, 256, 0, stream>>>(h, Wt1, Ps, Pd, N);

    if (ws_size >= need_full) {
        // ---- CSR build ----
        hipMemsetAsync(dcnt, 0, 64 * 4, stream);
        count_kernel<<<gE, 256, 0, stream>>>(dst, cnt, rank, E);
        scan1<<<Nb, 1024, 0, stream>>>(cnt, off, bsum, N);
        scan2<<<1, 64, 0, stream>>>(bsum, bofs, Nb);
        scan3<<<(N + 256) / 256, 256, 0, stream>>>(off, bofs, N, E);
        scatter_src<<<gE, 256, 0, stream>>>(dst, src, rank, off, csr_src, E);
        deghist<<<(N + 255) / 256, 256, 0, stream>>>(cnt, dcnt, dnr, N);
        degscan<<<1, 64, 0, stream>>>(dcnt, dofs);
        degscatter<<<(N + 255) / 256, 256, 0, stream>>>(cnt, dnr, dofs, nodeorder, N);
        // ---- fused gather: one wave per node, feature per lane ----
        gather_kernel<<<(N + 3) / 4, 256, 0, stream>>>(
            csr_src, off, nodeorder, x, Ps, Pd, Wt1, Wt2, be1, be2,
            ln_g, ln_b, Wx, bx, Wg, bg, agg_h, agg_x, N);
    } else {
        // ---- fallback: atomic aggregation ----
        hipMemsetAsync(agg_h, 0, (size_t)N * 67 * 4, stream);
        count_kernel<<<gE, 256, 0, stream>>>(dst, cnt, nullptr, E);
        edge_kernel_atomic<<<gE, 256, 0, stream>>>(src, dst, x, Ps, Pd, Wt1, Wt2,
                                                   be1, be2, ln_g, ln_b, Wx, bx,
                                                   Wg, bg, agg_h, agg_x, E);
    }

    node_kernel<<<gN64, 256, 0, stream>>>(h, x, agg_h, agg_x, cnt,
                                          Wht1, Wht2, bh1, bh2, (float*)d_out, N);
}

// Round 7
// 701.219 us; speedup vs baseline: 1.6611x; 1.0430x over previous
//
#include <hip/hip_runtime.h>
#include <math.h>

#define HID 64
#define DF  128

__device__ __forceinline__ float silu_f(float v) {
    return v / (1.0f + __expf(-v));
}

// wave-wide (64-lane) sum reduction
__device__ __forceinline__ float wredsum(float v) {
#pragma unroll
    for (int d = 1; d < 64; d <<= 1) v += __shfl_xor(v, d, 64);
    return v;
}

// 4 simultaneous wave-wide sums: one 6-level tree, 4-way ILP per level
__device__ __forceinline__ void wredsum4(float& a, float& b, float& c, float& d) {
#pragma unroll
    for (int t = 1; t < 64; t <<= 1) {
        a += __shfl_xor(a, t, 64);
        b += __shfl_xor(b, t, 64);
        c += __shfl_xor(c, t, 64);
        d += __shfl_xor(d, t, 64);
    }
}

// ---------------------------------------------------------------------------
// Weight transposes: [k][f]-major layouts.
// ---------------------------------------------------------------------------
__global__ void prep_weights(const float* __restrict__ We1, const float* __restrict__ We2,
                             const float* __restrict__ Wh1, const float* __restrict__ Wh2,
                             float* __restrict__ Wt1, float* __restrict__ Wt2,
                             float* __restrict__ Wht1, float* __restrict__ Wht2) {
    int i = blockIdx.x * 256 + threadIdx.x;
    if (i < 257 * 64) {
        int k = i >> 6, f = i & 63;
        Wt1[i] = We1[f * 257 + k];
        return;
    }
    int j = i - 257 * 64;
    if (j < 64 * 64) {
        int k = j >> 6, f = j & 63;
        Wt2[j] = We2[f * 64 + k];
        return;
    }
    j -= 64 * 64;
    if (j < 192 * 64) {
        int k = j >> 6, f = j & 63;
        Wht1[j] = Wh1[f * 192 + k];
        return;
    }
    j -= 192 * 64;
    if (j < 64 * 128) {
        int f = j >> 7, c = j & 127;
        Wht2[j] = Wh2[c * 64 + f];
        return;
    }
}

// ---------------------------------------------------------------------------
// CSR build
// ---------------------------------------------------------------------------
__global__ __launch_bounds__(256) void count_kernel(const int* __restrict__ dst,
                                                    int* __restrict__ cnt,
                                                    int* __restrict__ rank, int E) {
    int e = blockIdx.x * 256 + threadIdx.x;
    if (e >= E) return;
    int r = atomicAdd(&cnt[dst[e]], 1);
    if (rank) rank[e] = r;
}

__global__ __launch_bounds__(1024) void scan1(const int* __restrict__ cnt,
                                              int* __restrict__ off,
                                              int* __restrict__ bsum, int N) {
    __shared__ int sm[1024];
    int tid = threadIdx.x;
    int i = blockIdx.x * 1024 + tid;
    int v = (i < N) ? cnt[i] : 0;
    sm[tid] = v;
    __syncthreads();
    for (int ofs = 1; ofs < 1024; ofs <<= 1) {
        int t = (tid >= ofs) ? sm[tid - ofs] : 0;
        __syncthreads();
        sm[tid] += t;
        __syncthreads();
    }
    if (i < N) off[i] = sm[tid] - v;
    if (tid == 1023) bsum[blockIdx.x] = sm[1023];
}

__global__ void scan2(const int* __restrict__ bsum, int* __restrict__ bofs, int Nb) {
    if (threadIdx.x == 0) {
        int s = 0;
        for (int b = 0; b < Nb; ++b) { bofs[b] = s; s += bsum[b]; }
    }
}

__global__ __launch_bounds__(256) void scan3(int* __restrict__ off,
                                             const int* __restrict__ bofs,
                                             int N, int E) {
    int i = blockIdx.x * 256 + threadIdx.x;
    if (i > N) return;
    if (i == N) off[N] = E;
    else off[i] += bofs[i >> 10];
}

__global__ __launch_bounds__(256) void deghist(const int* __restrict__ cnt,
                                               int* __restrict__ dcnt,
                                               int* __restrict__ dnr, int N) {
    int n = blockIdx.x * 256 + threadIdx.x;
    if (n >= N) return;
    int b = min(cnt[n], 63);
    dnr[n] = atomicAdd(&dcnt[b], 1);
}

__global__ void degscan(const int* __restrict__ dcnt, int* __restrict__ dofs) {
    if (threadIdx.x == 0) {
        int s = 0;
        for (int b = 0; b < 64; ++b) { dofs[b] = s; s += dcnt[b]; }
    }
}

__global__ __launch_bounds__(256) void degscatter(const int* __restrict__ cnt,
                                                  const int* __restrict__ dnr,
                                                  const int* __restrict__ dofs,
                                                  int* __restrict__ nodeorder, int N) {
    int n = blockIdx.x * 256 + threadIdx.x;
    if (n >= N) return;
    int b = min(cnt[n], 63);
    nodeorder[dofs[b] + dnr[n]] = n;
}

// csr_src[off[dst[e]] + rank[e]] = src[e]
__global__ __launch_bounds__(256) void scatter_src(const int* __restrict__ dst,
                                                   const int* __restrict__ srcI,
                                                   const int* __restrict__ rank,
                                                   const int* __restrict__ off,
                                                   int* __restrict__ csr_src, int E) {
    int e = blockIdx.x * 256 + threadIdx.x;
    if (e >= E) return;
    csr_src[off[dst[e]] + rank[e]] = srcI[e];
}

// ---------------------------------------------------------------------------
// node_pre (wave-feature-split): 4 waves over 64 nodes; wave w does 16 feats.
// ---------------------------------------------------------------------------
__global__ __launch_bounds__(256) void node_pre(const float* __restrict__ h,
                                                const float* __restrict__ Wt1,
                                                float* __restrict__ Ps,
                                                float* __restrict__ Pd, int N) {
    int lane = threadIdx.x & 63;
    int w = __builtin_amdgcn_readfirstlane(threadIdx.x >> 6);
    int n = blockIdx.x * 64 + lane;
    if (n >= N) return;
    int f0 = w * 16;
    float accS[16], accD[16];
#pragma unroll
    for (int j = 0; j < 16; ++j) { accS[j] = 0.f; accD[j] = 0.f; }
    const float4* row = (const float4*)(h + (size_t)n * DF);
    for (int k4 = 0; k4 < DF / 4; ++k4) {
        float4 v = row[k4];
        float hv4[4] = {v.x, v.y, v.z, v.w};
#pragma unroll
        for (int jj = 0; jj < 4; ++jj) {
            int k = k4 * 4 + jj;
            float hv = hv4[jj];
#pragma unroll
            for (int j = 0; j < 16; ++j) {
                accS[j] = fmaf(hv, Wt1[k * HID + f0 + j], accS[j]);
                accD[j] = fmaf(hv, Wt1[(DF + k) * HID + f0 + j], accD[j]);
            }
        }
    }
    float4* ps = (float4*)(Ps + (size_t)n * HID + f0);
    float4* pd = (float4*)(Pd + (size_t)n * HID + f0);
#pragma unroll
    for (int j4 = 0; j4 < 4; ++j4) {
        ps[j4] = make_float4(accS[4 * j4], accS[4 * j4 + 1], accS[4 * j4 + 2], accS[4 * j4 + 3]);
        pd[j4] = make_float4(accD[4 * j4], accD[4 * j4 + 1], accD[4 * j4 + 2], accD[4 * j4 + 3]);
    }
}

// ---------------------------------------------------------------------------
// Gather v4: ONE WAVE per dst node, ONE FEATURE per lane.
//  - We2 column (64 floats) PINNED in VGPRs via opaque asm (no remat, no
//    per-edge L1 weight streaming). launch_bounds(256,2) -> 256-VGPR cap,
//    zero spill pressure.
//  - All 4 wave reductions fused into ONE 6-level shfl tree per edge:
//    S1=sum(m), S2=sum(m^2), Sg=sum(m*g*wg), Sx=sum(m*g*wx); gate dots
//    reconstructed algebraically via loop-invariant sums (Cg,Cx,Cbg,Cbx).
// ---------------------------------------------------------------------------
__global__ __launch_bounds__(256, 2) void gather_kernel(
    const int* __restrict__ csr_src, const int* __restrict__ off,
    const int* __restrict__ nodeorder, const float* __restrict__ x,
    const float* __restrict__ Ps, const float* __restrict__ Pd,
    const float* __restrict__ Wt1, const float* __restrict__ Wt2,
    const float* __restrict__ be1, const float* __restrict__ be2,
    const float* __restrict__ ln_g, const float* __restrict__ ln_b,
    const float* __restrict__ Wx, const float* __restrict__ bx,
    const float* __restrict__ Wg, const float* __restrict__ bg,
    float* __restrict__ agg_h, float* __restrict__ agg_x, int N) {
    __shared__ float smz[4][64];
    const int lane = threadIdx.x & 63;
    const int wslot = threadIdx.x >> 6;
    const int wid = blockIdx.x * 4 + wslot;
    if (wid >= N) return;
    const int n = nodeorder[wid];
    const int beg = off[n], end = off[n + 1];

    // pinned per-lane weight column: w[k] = We2[lane][k]
    float w[64];
#pragma unroll
    for (int k = 0; k < 64; ++k) w[k] = Wt2[k * HID + lane];
#pragma unroll
    for (int k = 0; k < 64; ++k) asm volatile("" : "+v"(w[k]));

    const float basef = Pd[(size_t)n * HID + lane] + be1[lane];
    const float colWf = Wt1[256 * HID + lane];   // We1[:,256] (d_sq column)
    const float be2f = be2[lane];
    const float gf = ln_g[lane], bf = ln_b[lane];
    const float wgf = Wg[lane], wxf = Wx[lane];
    const float cgf = gf * wgf, cxf = gf * wxf;  // per-lane gate-weight products
    const float bgs = bg[0], bxs = bx[0];
    const float xd0 = x[n * 3], xd1 = x[n * 3 + 1], xd2 = x[n * 3 + 2];

    // loop-invariant wave-uniform sums (one pre-loop reduction)
    float Cg = cgf, Cx = cxf, Cbg = bf * wgf, Cbx = bf * wxf;
    wredsum4(Cg, Cx, Cbg, Cbx);

    float acc = 0.f, ax0 = 0.f, ax1 = 0.f, ax2 = 0.f;

    if (beg < end) {
        // software-pipelined: prefetch edge i+1's src/x/Ps during edge i
        int s = csr_src[beg];
        float xs0 = x[s * 3], xs1 = x[s * 3 + 1], xs2 = x[s * 3 + 2];
        float psv = Ps[(size_t)s * HID + lane];

        for (int i = beg; i < end; ++i) {
            int ip = (i + 1 < end) ? i + 1 : i;
            int s_nx = csr_src[ip];
            float xn0 = x[s_nx * 3], xn1 = x[s_nx * 3 + 1], xn2 = x[s_nx * 3 + 2];
            float psn = Ps[(size_t)s_nx * HID + lane];

            float r0 = xs0 - xd0, r1 = xs1 - xd1, r2 = xs2 - xd2;
            float dsq = r0 * r0 + r1 * r1 + r2 * r2;
            float inv = 1.0f / (sqrtf(dsq) + 1e-8f);

            float z = silu_f(psv + basef + dsq * colWf);
            smz[wslot][lane] = z;
            __builtin_amdgcn_wave_barrier();

            // m[lane] = be2 + sum_k z_k * We2[lane][k]  (4 partial chains)
            float m0 = be2f, m1 = 0.f, m2 = 0.f, m3 = 0.f;
#pragma unroll
            for (int k4 = 0; k4 < 16; ++k4) {
                float4 zc = *(const float4*)&smz[wslot][k4 * 4];
                m0 = fmaf(zc.x, w[4 * k4 + 0], m0);
                m1 = fmaf(zc.y, w[4 * k4 + 1], m1);
                m2 = fmaf(zc.z, w[4 * k4 + 2], m2);
                m3 = fmaf(zc.w, w[4 * k4 + 3], m3);
            }
            __builtin_amdgcn_wave_barrier();  // next iter's write stays after reads
            float m = silu_f((m0 + m1) + (m2 + m3));

            // ONE fused reduction stage: mean, mean-square, both gate dots
            float S1 = m, S2 = m * m, Sg = m * cgf, Sx = m * cxf;
            wredsum4(S1, S2, Sg, Sx);

            float mu = S1 * (1.0f / HID);
            float var = S2 * (1.0f / HID) - mu * mu;
            float rstd = 1.0f / sqrtf(var + 1e-5f);
            float dg = fmaf(rstd, Sg - mu * Cg, Cbg);   // = sum(mn*wg)
            float dx = fmaf(rstd, Sx - mu * Cx, Cbx);   // = sum(mn*wx)

            float alpha = 1.0f / (1.0f + __expf(-(dg + bgs)));
            float ta = __expf(2.0f * fmaf(alpha, dx, bxs));
            float cw = 1.0f - 2.0f / (ta + 1.0f);

            float mn = fmaf((m - mu) * rstd, gf, bf);
            acc = fmaf(mn, alpha, acc);
            float rc = inv * cw;
            ax0 = fmaf(r0, rc, ax0);
            ax1 = fmaf(r1, rc, ax1);
            ax2 = fmaf(r2, rc, ax2);

            xs0 = xn0; xs1 = xn1; xs2 = xn2; psv = psn;
        }
    }

    agg_h[(size_t)n * HID + lane] = acc;
    if (lane == 0) {
        agg_x[n * 3 + 0] = ax0;
        agg_x[n * 3 + 1] = ax1;
        agg_x[n * 3 + 2] = ax2;
    }
}

// ---------------------------------------------------------------------------
// Fallback edge kernel (atomic aggregation) — only if ws too small for CSR.
// ---------------------------------------------------------------------------
__global__ __launch_bounds__(256) void edge_kernel_atomic(
    const int* __restrict__ src, const int* __restrict__ dst,
    const float* __restrict__ x,
    const float* __restrict__ Ps, const float* __restrict__ Pd,
    const float* __restrict__ Wt1, const float* __restrict__ Wt2,
    const float* __restrict__ be1, const float* __restrict__ be2,
    const float* __restrict__ ln_g, const float* __restrict__ ln_b,
    const float* __restrict__ Wx, const float* __restrict__ bx,
    const float* __restrict__ Wg, const float* __restrict__ bg,
    float* __restrict__ agg_h, float* __restrict__ agg_x, int E) {
    int e = blockIdx.x * 256 + threadIdx.x;
    if (e >= E) return;
    int s = src[e], d = dst[e];
    float r0 = x[s * 3] - x[d * 3], r1 = x[s * 3 + 1] - x[d * 3 + 1], r2 = x[s * 3 + 2] - x[d * 3 + 2];
    float dsq = r0 * r0 + r1 * r1 + r2 * r2;
    float inv = 1.0f / (sqrtf(dsq) + 1e-8f);
    float rn0 = r0 * inv, rn1 = r1 * inv, rn2 = r2 * inv;
    float z[HID];
    const float4* ps = (const float4*)(Ps + (size_t)s * HID);
    const float4* pd = (const float4*)(Pd + (size_t)d * HID);
    const float* colW = Wt1 + 256 * HID;
#pragma unroll
    for (int f4 = 0; f4 < HID / 4; ++f4) {
        float4 a = ps[f4];
        float4 b = pd[f4];
        float av[4] = {a.x, a.y, a.z, a.w};
        float bv[4] = {b.x, b.y, b.z, b.w};
#pragma unroll
        for (int j = 0; j < 4; ++j) {
            int f = 4 * f4 + j;
            z[f] = silu_f(av[j] + bv[j] + be1[f] + dsq * colW[f]);
        }
    }
    float m[HID];
#pragma unroll
    for (int f = 0; f < HID; ++f) m[f] = be2[f];
#pragma unroll
    for (int k = 0; k < HID; ++k) {
        float zv = z[k];
#pragma unroll
        for (int f = 0; f < HID; ++f) m[f] = fmaf(zv, Wt2[k * HID + f], m[f]);
    }
#pragma unroll
    for (int f = 0; f < HID; ++f) m[f] = silu_f(m[f]);
    float mu = 0.f;
#pragma unroll
    for (int f = 0; f < HID; ++f) mu += m[f];
    mu *= (1.0f / HID);
    float var = 0.f;
#pragma unroll
    for (int f = 0; f < HID; ++f) {
        float t = m[f] - mu;
        var = fmaf(t, t, var);
    }
    var *= (1.0f / HID);
    float rstd = 1.0f / sqrtf(var + 1e-5f);
#pragma unroll
    for (int f = 0; f < HID; ++f) m[f] = (m[f] - mu) * rstd * ln_g[f] + ln_b[f];
    float dotg = 0.f, dotx = 0.f;
#pragma unroll
    for (int f = 0; f < HID; ++f) {
        dotg = fmaf(m[f], Wg[f], dotg);
        dotx = fmaf(m[f], Wx[f], dotx);
    }
    float alpha = 1.0f / (1.0f + __expf(-(dotg + bg[0])));
    float ta = __expf(2.0f * fmaf(alpha, dotx, bx[0]));
    float cw = 1.0f - 2.0f / (ta + 1.0f);
    float* ah = agg_h + (size_t)d * HID;
#pragma unroll
    for (int f = 0; f < HID; ++f) atomicAdd(&ah[f], m[f] * alpha);
    atomicAdd(&agg_x[d * 3 + 0], rn0 * cw);
    atomicAdd(&agg_x[d * 3 + 1], rn1 * cw);
    atomicAdd(&agg_x[d * 3 + 2], rn2 * cw);
}

// ---------------------------------------------------------------------------
// node_kernel (wave-feature-split, LDS hh exchange)
// ---------------------------------------------------------------------------
__global__ __launch_bounds__(256) void node_kernel(
    const float* __restrict__ h, const float* __restrict__ x,
    const float* __restrict__ agg_h, const float* __restrict__ agg_x,
    const int* __restrict__ degI,
    const float* __restrict__ Wht1, const float* __restrict__ Wht2,
    const float* __restrict__ bh1, const float* __restrict__ bh2,
    float* __restrict__ out, int N) {
    __shared__ float hh[64 * 65];
    int lane = threadIdx.x & 63;
    int w = __builtin_amdgcn_readfirstlane(threadIdx.x >> 6);
    int n = blockIdx.x * 64 + lane;

    if (n < N) {
        int f0 = w * 16;
        float t[16];
#pragma unroll
        for (int j = 0; j < 16; ++j) t[j] = bh1[f0 + j];
        const float4* rowH = (const float4*)(h + (size_t)n * DF);
        for (int k4 = 0; k4 < DF / 4; ++k4) {
            float4 v = rowH[k4];
            float hv4[4] = {v.x, v.y, v.z, v.w};
#pragma unroll
            for (int jj = 0; jj < 4; ++jj) {
                int k = k4 * 4 + jj;
                float hv = hv4[jj];
#pragma unroll
                for (int j = 0; j < 16; ++j) t[j] = fmaf(hv, Wht1[k * HID + f0 + j], t[j]);
            }
        }
        const float4* rowA = (const float4*)(agg_h + (size_t)n * HID);
        for (int k4 = 0; k4 < HID / 4; ++k4) {
            float4 v = rowA[k4];
            float hv4[4] = {v.x, v.y, v.z, v.w};
#pragma unroll
            for (int jj = 0; jj < 4; ++jj) {
                int k = DF + k4 * 4 + jj;
                float hv = hv4[jj];
#pragma unroll
                for (int j = 0; j < 16; ++j) t[j] = fmaf(hv, Wht1[k * HID + f0 + j], t[j]);
            }
        }
#pragma unroll
        for (int j = 0; j < 16; ++j) hh[lane * 65 + f0 + j] = silu_f(t[j]);
    }
    __syncthreads();
    if (n >= N) return;

    int c0 = w * 32;
    float o[32];
#pragma unroll
    for (int j = 0; j < 32; ++j) o[j] = bh2[c0 + j];
    for (int k = 0; k < HID; ++k) {
        float hv = hh[lane * 65 + k];
#pragma unroll
        for (int j = 0; j < 32; ++j) o[j] = fmaf(hv, Wht2[k * DF + c0 + j], o[j]);
    }
    float* oh = out + (size_t)n * DF + c0;
    const float* hrow = h + (size_t)n * DF + c0;
#pragma unroll
    for (int j4 = 0; j4 < 8; ++j4) {
        float4 hv = ((const float4*)hrow)[j4];
        float4 r;
        r.x = hv.x + o[4 * j4];
        r.y = hv.y + o[4 * j4 + 1];
        r.z = hv.z + o[4 * j4 + 2];
        r.w = hv.w + o[4 * j4 + 3];
        ((float4*)oh)[j4] = r;
    }
    if (w == 0) {
        float dv = (float)degI[n];
        float invd = 1.0f / fmaxf(dv, 1.0f);
        float* ox = out + (size_t)N * DF + (size_t)n * 3;
        ox[0] = x[n * 3 + 0] + agg_x[n * 3 + 0] * invd;
        ox[1] = x[n * 3 + 1] + agg_x[n * 3 + 1] * invd;
        ox[2] = x[n * 3 + 2] + agg_x[n * 3 + 2] * invd;
    }
}

extern "C" void kernel_launch(void* const* d_in, const int* in_sizes, int n_in,
                              void* d_out, int out_size, void* d_ws, size_t ws_size,
                              hipStream_t stream) {
    const float* h    = (const float*)d_in[0];
    const float* x    = (const float*)d_in[1];
    const int*   ei   = (const int*)d_in[2];
    const float* We1  = (const float*)d_in[3];
    const float* be1  = (const float*)d_in[4];
    const float* We2  = (const float*)d_in[5];
    const float* be2  = (const float*)d_in[6];
    const float* ln_g = (const float*)d_in[7];
    const float* ln_b = (const float*)d_in[8];
    const float* Wh1  = (const float*)d_in[9];
    const float* bh1  = (const float*)d_in[10];
    const float* Wh2  = (const float*)d_in[11];
    const float* bh2  = (const float*)d_in[12];
    const float* Wx   = (const float*)d_in[13];
    const float* bx   = (const float*)d_in[14];
    const float* Wg   = (const float*)d_in[15];
    const float* bg   = (const float*)d_in[16];

    const int E = in_sizes[2] / 2;
    const int N = in_sizes[0] / DF;
    const int* src = ei;
    const int* dst = ei + E;

    // ---- workspace carve (16B aligned regions) ----
    char* base = (char*)d_ws;
    size_t o = 0;
    auto carve = [&](size_t bytes) -> void* {
        void* r = base + o;
        o = (o + bytes + 15) & ~(size_t)15;
        return r;
    };
    float* agg_h = (float*)carve((size_t)N * HID * 4);
    float* agg_x = (float*)carve((size_t)N * 3 * 4);
    float* Wt1   = (float*)carve(257 * 64 * 4);
    float* Wt2   = (float*)carve(64 * 64 * 4);
    float* Wht1  = (float*)carve(192 * 64 * 4);
    float* Wht2  = (float*)carve(64 * 128 * 4);
    int*   cnt   = (int*)carve((size_t)N * 4);
    int*   off   = (int*)carve(((size_t)N + 1) * 4);
    int*   bsum  = (int*)carve(256 * 4);
    int*   bofs  = (int*)carve(256 * 4);
    int*   dcnt  = (int*)carve(64 * 4);
    int*   dofs  = (int*)carve(64 * 4);
    int*   dnr   = (int*)carve((size_t)N * 4);
    int*   nodeorder = (int*)carve((size_t)N * 4);
    int*   rank  = (int*)carve((size_t)E * 4);
    int*   csr_src = (int*)carve((size_t)E * 4);
    size_t need_full = o;

    // Ps/Pd live in d_out (N*128 <= out_size N*131); d_out is fully
    // overwritten by node_kernel afterwards.
    float* Ps = (float*)d_out;
    float* Pd = Ps + (size_t)N * HID;

    const int gE  = (E + 255) / 256;
    const int Nb  = (N + 1023) / 1024;
    const int gN64 = (N + 63) / 64;

    hipMemsetAsync(cnt, 0, (size_t)N * 4, stream);
    prep_weights<<<(41024 + 255) / 256, 256, 0, stream>>>(We1, We2, Wh1, Wh2,
                                                          Wt1, Wt2, Wht1, Wht2);
    node_pre<<<gN64, 256, 0, stream>>>(h, Wt1, Ps, Pd, N);

    if (ws_size >= need_full) {
        // ---- CSR build ----
        hipMemsetAsync(dcnt, 0, 64 * 4, stream);
        count_kernel<<<gE, 256, 0, stream>>>(dst, cnt, rank, E);
        scan1<<<Nb, 1024, 0, stream>>>(cnt, off, bsum, N);
        scan2<<<1, 64, 0, stream>>>(bsum, bofs, Nb);
        scan3<<<(N + 256) / 256, 256, 0, stream>>>(off, bofs, N, E);
        scatter_src<<<gE, 256, 0, stream>>>(dst, src, rank, off, csr_src, E);
        deghist<<<(N + 255) / 256, 256, 0, stream>>>(cnt, dcnt, dnr, N);
        degscan<<<1, 64, 0, stream>>>(dcnt, dofs);
        degscatter<<<(N + 255) / 256, 256, 0, stream>>>(cnt, dnr, dofs, nodeorder, N);
        // ---- fused gather: one wave per node, feature per lane ----
        gather_kernel<<<(N + 3) / 4, 256, 0, stream>>>(
            csr_src, off, nodeorder, x, Ps, Pd, Wt1, Wt2, be1, be2,
            ln_g, ln_b, Wx, bx, Wg, bg, agg_h, agg_x, N);
    } else {
        // ---- fallback: atomic aggregation ----
        hipMemsetAsync(agg_h, 0, (size_t)N * 67 * 4, stream);
        count_kernel<<<gE, 256, 0, stream>>>(dst, cnt, nullptr, E);
        edge_kernel_atomic<<<gE, 256, 0, stream>>>(src, dst, x, Ps, Pd, Wt1, Wt2,
                                                   be1, be2, ln_g, ln_b, Wx, bx,
                                                   Wg, bg, agg_h, agg_x, E);
    }

    node_kernel<<<gN64, 256, 0, stream>>>(h, x, agg_h, agg_x, cnt,
                                          Wht1, Wht2, bh1, bh2, (float*)d_out, N);
}

// Round 8
// 466.609 us; speedup vs baseline: 2.4963x; 1.5028x over previous
//
#include <hip/hip_runtime.h>
#include <math.h>

#define HID 64
#define DF  128

typedef __attribute__((ext_vector_type(8))) short short8v;   // 8 bf16
typedef __attribute__((ext_vector_type(4))) float float4v;

__device__ __forceinline__ float silu_f(float v) {
    return v * __builtin_amdgcn_rcpf(1.0f + __expf(-v));
}

__device__ __forceinline__ unsigned short f2bf(float f) {   // RNE f32->bf16
    unsigned u = __float_as_uint(f);
    u += 0x7FFFu + ((u >> 16) & 1u);
    return (unsigned short)(u >> 16);
}

// 4 simultaneous wave-wide sums: one 6-level tree, 4-way ILP per level
__device__ __forceinline__ void wredsum4(float& a, float& b, float& c, float& d) {
#pragma unroll
    for (int t = 1; t < 64; t <<= 1) {
        a += __shfl_xor(a, t, 64);
        b += __shfl_xor(b, t, 64);
        c += __shfl_xor(c, t, 64);
        d += __shfl_xor(d, t, 64);
    }
}

// ---------------------------------------------------------------------------
// Weight transposes + bf16 MFMA A-fragment pack of We2.
// WbfA flat index j = ((t*2+kc)*64 + lane)*8 + jj  holds
//   bf16( We2[t*16 + (lane&15)][kc*32 + (lane>>4)*8 + jj] )
// (A-frag layout for mfma_f32_16x16x32_bf16: row=lane&15, k=(lane>>4)*8+j)
// ---------------------------------------------------------------------------
__global__ void prep_weights(const float* __restrict__ We1, const float* __restrict__ We2,
                             const float* __restrict__ Wh1, const float* __restrict__ Wh2,
                             float* __restrict__ Wt1, float* __restrict__ Wt2,
                             float* __restrict__ Wht1, float* __restrict__ Wht2,
                             unsigned short* __restrict__ WbfA) {
    int i = blockIdx.x * 256 + threadIdx.x;
    if (i < 257 * 64) {
        int k = i >> 6, f = i & 63;
        Wt1[i] = We1[f * 257 + k];
        return;
    }
    int j = i - 257 * 64;
    if (j < 64 * 64) {
        int k = j >> 6, f = j & 63;
        Wt2[j] = We2[f * 64 + k];
        return;
    }
    j -= 64 * 64;
    if (j < 192 * 64) {
        int k = j >> 6, f = j & 63;
        Wht1[j] = Wh1[f * 192 + k];
        return;
    }
    j -= 192 * 64;
    if (j < 64 * 128) {
        int f = j >> 7, c = j & 127;
        Wht2[j] = Wh2[c * 64 + f];
        return;
    }
    j -= 64 * 128;
    if (j < 4096) {
        int jj = j & 7, lane = (j >> 3) & 63, kc = (j >> 9) & 1, t = (j >> 10) & 3;
        int f = t * 16 + (lane & 15);
        int k = kc * 32 + ((lane >> 4) * 8) + jj;
        WbfA[j] = f2bf(We2[f * 64 + k]);
        return;
    }
}

// ---------------------------------------------------------------------------
// CSR build
// ---------------------------------------------------------------------------
__global__ __launch_bounds__(256) void count_kernel(const int* __restrict__ dst,
                                                    int* __restrict__ cnt,
                                                    int* __restrict__ rank, int E) {
    int e = blockIdx.x * 256 + threadIdx.x;
    if (e >= E) return;
    int r = atomicAdd(&cnt[dst[e]], 1);
    if (rank) rank[e] = r;
}

__global__ __launch_bounds__(1024) void scan1(const int* __restrict__ cnt,
                                              int* __restrict__ off,
                                              int* __restrict__ bsum, int N) {
    __shared__ int sm[1024];
    int tid = threadIdx.x;
    int i = blockIdx.x * 1024 + tid;
    int v = (i < N) ? cnt[i] : 0;
    sm[tid] = v;
    __syncthreads();
    for (int ofs = 1; ofs < 1024; ofs <<= 1) {
        int t = (tid >= ofs) ? sm[tid - ofs] : 0;
        __syncthreads();
        sm[tid] += t;
        __syncthreads();
    }
    if (i < N) off[i] = sm[tid] - v;
    if (tid == 1023) bsum[blockIdx.x] = sm[1023];
}

__global__ void scan2(const int* __restrict__ bsum, int* __restrict__ bofs, int Nb) {
    if (threadIdx.x == 0) {
        int s = 0;
        for (int b = 0; b < Nb; ++b) { bofs[b] = s; s += bsum[b]; }
    }
}

__global__ __launch_bounds__(256) void scan3(int* __restrict__ off,
                                             const int* __restrict__ bofs,
                                             int N, int E) {
    int i = blockIdx.x * 256 + threadIdx.x;
    if (i > N) return;
    if (i == N) off[N] = E;
    else off[i] += bofs[i >> 10];
}

__global__ __launch_bounds__(256) void deghist(const int* __restrict__ cnt,
                                               int* __restrict__ dcnt,
                                               int* __restrict__ dnr, int N) {
    int n = blockIdx.x * 256 + threadIdx.x;
    if (n >= N) return;
    int b = min(cnt[n], 63);
    dnr[n] = atomicAdd(&dcnt[b], 1);
}

__global__ void degscan(const int* __restrict__ dcnt, int* __restrict__ dofs) {
    if (threadIdx.x == 0) {
        int s = 0;
        for (int b = 0; b < 64; ++b) { dofs[b] = s; s += dcnt[b]; }
    }
}

__global__ __launch_bounds__(256) void degscatter(const int* __restrict__ cnt,
                                                  const int* __restrict__ dnr,
                                                  const int* __restrict__ dofs,
                                                  int* __restrict__ nodeorder, int N) {
    int n = blockIdx.x * 256 + threadIdx.x;
    if (n >= N) return;
    int b = min(cnt[n], 63);
    nodeorder[dofs[b] + dnr[n]] = n;
}

__global__ __launch_bounds__(256) void scatter_src(const int* __restrict__ dst,
                                                   const int* __restrict__ srcI,
                                                   const int* __restrict__ rank,
                                                   const int* __restrict__ off,
                                                   int* __restrict__ csr_src, int E) {
    int e = blockIdx.x * 256 + threadIdx.x;
    if (e >= E) return;
    csr_src[off[dst[e]] + rank[e]] = srcI[e];
}

// ---------------------------------------------------------------------------
// node_pre (wave-feature-split): 4 waves over 64 nodes; wave w does 16 feats.
// ---------------------------------------------------------------------------
__global__ __launch_bounds__(256) void node_pre(const float* __restrict__ h,
                                                const float* __restrict__ Wt1,
                                                float* __restrict__ Ps,
                                                float* __restrict__ Pd, int N) {
    int lane = threadIdx.x & 63;
    int w = __builtin_amdgcn_readfirstlane(threadIdx.x >> 6);
    int n = blockIdx.x * 64 + lane;
    if (n >= N) return;
    int f0 = w * 16;
    float accS[16], accD[16];
#pragma unroll
    for (int j = 0; j < 16; ++j) { accS[j] = 0.f; accD[j] = 0.f; }
    const float4* row = (const float4*)(h + (size_t)n * DF);
    for (int k4 = 0; k4 < DF / 4; ++k4) {
        float4 v = row[k4];
        float hv4[4] = {v.x, v.y, v.z, v.w};
#pragma unroll
        for (int jj = 0; jj < 4; ++jj) {
            int k = k4 * 4 + jj;
            float hv = hv4[jj];
#pragma unroll
            for (int j = 0; j < 16; ++j) {
                accS[j] = fmaf(hv, Wt1[k * HID + f0 + j], accS[j]);
                accD[j] = fmaf(hv, Wt1[(DF + k) * HID + f0 + j], accD[j]);
            }
        }
    }
    float4* ps = (float4*)(Ps + (size_t)n * HID + f0);
    float4* pd = (float4*)(Pd + (size_t)n * HID + f0);
#pragma unroll
    for (int j4 = 0; j4 < 4; ++j4) {
        ps[j4] = make_float4(accS[4 * j4], accS[4 * j4 + 1], accS[4 * j4 + 2], accS[4 * j4 + 3]);
        pd[j4] = make_float4(accD[4 * j4], accD[4 * j4 + 1], accD[4 * j4 + 2], accD[4 * j4 + 3]);
    }
}

// ---------------------------------------------------------------------------
// Gather v5: ONE WAVE per dst node, 16 EDGES per batch via bf16 MFMA.
//  z (feature=lane) -> LDS bf16 [e][k] -> B-frags; We2 resident as 8 A-frags.
//  D layout (verified): col=lane&15=edge, row=(lane>>4)*4+reg -> each lane
//  holds 16 m-values of ONE edge; LN/gate sums = in-reg partials + 2 shfls.
// ---------------------------------------------------------------------------
__global__ __launch_bounds__(256) void gather_kernel(
    const int* __restrict__ csr_src, const int* __restrict__ off,
    const int* __restrict__ nodeorder, const float* __restrict__ x,
    const float* __restrict__ Ps, const float* __restrict__ Pd,
    const float* __restrict__ Wt1, const unsigned short* __restrict__ WbfA,
    const float* __restrict__ be1, const float* __restrict__ be2,
    const float* __restrict__ ln_g, const float* __restrict__ ln_b,
    const float* __restrict__ Wx, const float* __restrict__ bx,
    const float* __restrict__ Wg, const float* __restrict__ bg,
    float* __restrict__ agg_h, float* __restrict__ agg_x, int N) {
    __shared__ unsigned short zL[4][16][80];  // [wave][edge][k], 160B rows (16B-aligned frags)
    __shared__ int   smS[4][16];
    __shared__ float smD[4][16];

    const int lane = threadIdx.x & 63;
    const int wslot = threadIdx.x >> 6;
    const int wid = blockIdx.x * 4 + wslot;
    if (wid >= N) return;
    const int n = nodeorder[wid];
    const int beg = off[n], end = off[n + 1];

    // resident A fragments (We2 bf16)
    short8v a[4][2];
#pragma unroll
    for (int t = 0; t < 4; ++t)
#pragma unroll
        for (int kc = 0; kc < 2; ++kc)
            a[t][kc] = *(const short8v*)&WbfA[(((t * 2 + kc) * 64) + lane) * 8];

    // z-side per-lane params (feature = lane)
    const float basef = Pd[(size_t)n * HID + lane] + be1[lane];
    const float colWf = Wt1[256 * HID + lane];
    // m-side per-lane params (f_r = t*16 + (lane>>4)*4 + r)
    float be2r[16], gr[16], br[16], cgr[16], cxr[16];
#pragma unroll
    for (int t = 0; t < 4; ++t)
#pragma unroll
        for (int r = 0; r < 4; ++r) {
            int f = t * 16 + ((lane >> 4) << 2) + r;
            float g = ln_g[f];
            be2r[4 * t + r] = be2[f];
            gr[4 * t + r] = g;
            br[4 * t + r] = ln_b[f];
            cgr[4 * t + r] = g * Wg[f];
            cxr[4 * t + r] = g * Wx[f];
        }
    const float bgs = bg[0], bxs = bx[0];
    const float xd0 = x[n * 3], xd1 = x[n * 3 + 1], xd2 = x[n * 3 + 2];

    // wave-uniform loop invariants (feature=lane view)
    float Cg = ln_g[lane] * Wg[lane], Cx = ln_g[lane] * Wx[lane];
    float Cbg = ln_b[lane] * Wg[lane], Cbx = ln_b[lane] * Wx[lane];
    wredsum4(Cg, Cx, Cbg, Cbx);

    float4v acc[4];
#pragma unroll
    for (int t = 0; t < 4; ++t) acc[t] = (float4v){0.f, 0.f, 0.f, 0.f};
    float ax0 = 0.f, ax1 = 0.f, ax2 = 0.f;
    const float g0 = (lane < 16) ? 1.0f : 0.0f;
    const int e16 = lane & 15;

    for (int base = beg; base < end; base += 16) {
        int idx = base + e16;
        float validf = (idx < end) ? 1.0f : 0.0f;
        int idxc = (idx < end) ? idx : (end - 1);
        int s = csr_src[idxc];
        float r0 = x[s * 3] - xd0, r1 = x[s * 3 + 1] - xd1, r2 = x[s * 3 + 2] - xd2;
        float dsq = r0 * r0 + r1 * r1 + r2 * r2;
        float inv = __builtin_amdgcn_rcpf(__builtin_amdgcn_sqrtf(dsq) + 1e-8f);
        smS[wslot][e16] = s;      // 4 groups write identical values
        smD[wslot][e16] = dsq;
        __builtin_amdgcn_wave_barrier();

        // z for 16 edges at this lane's feature -> LDS bf16
#pragma unroll
        for (int e = 0; e < 16; ++e) {
            int se = smS[wslot][e];
            float pv = Ps[(size_t)se * HID + lane];
            float dq = smD[wslot][e];
            float zt = pv + basef + dq * colWf;
            float zs = zt * __builtin_amdgcn_rcpf(1.0f + __expf(-zt));
            zL[wslot][e][lane] = f2bf(zs);
        }
        __builtin_amdgcn_wave_barrier();

        short8v b0 = *(const short8v*)&zL[wslot][e16][(lane >> 4) * 8];
        short8v b1 = *(const short8v*)&zL[wslot][e16][(lane >> 4) * 8 + 32];
        __builtin_amdgcn_wave_barrier();  // keep reads before next batch's writes

        float4v d[4];
#pragma unroll
        for (int t = 0; t < 4; ++t) {
            float4v c = (float4v){0.f, 0.f, 0.f, 0.f};
            c = __builtin_amdgcn_mfma_f32_16x16x32_bf16(a[t][0], b0, c, 0, 0, 0);
            c = __builtin_amdgcn_mfma_f32_16x16x32_bf16(a[t][1], b1, c, 0, 0, 0);
            d[t] = c;
        }

        // bias + silu + partial stats (this lane's 16 rows of edge e16)
        float ms[16];
        float S1 = 0.f, S2 = 0.f, Sg = 0.f, Sx = 0.f;
#pragma unroll
        for (int t = 0; t < 4; ++t)
#pragma unroll
            for (int r = 0; r < 4; ++r) {
                float mp = d[t][r] + be2r[4 * t + r];
                float v = mp * __builtin_amdgcn_rcpf(1.0f + __expf(-mp));
                ms[4 * t + r] = v;
                S1 += v;
                S2 = fmaf(v, v, S2);
                Sg = fmaf(v, cgr[4 * t + r], Sg);
                Sx = fmaf(v, cxr[4 * t + r], Sx);
            }
        // complete per-edge sums across the 4 row-groups (2 shfl levels)
#pragma unroll
        for (int mk = 16; mk < 64; mk <<= 1) {
            S1 += __shfl_xor(S1, mk, 64);
            S2 += __shfl_xor(S2, mk, 64);
            Sg += __shfl_xor(Sg, mk, 64);
            Sx += __shfl_xor(Sx, mk, 64);
        }

        float mu = S1 * (1.0f / HID);
        float var = S2 * (1.0f / HID) - mu * mu;
        float rstd = __builtin_amdgcn_rsqf(var + 1e-5f);
        float dg = fmaf(rstd, Sg - mu * Cg, Cbg);
        float dx = fmaf(rstd, Sx - mu * Cx, Cbx);
        float alpha = __builtin_amdgcn_rcpf(1.0f + __expf(-(dg + bgs))) * validf;
        float ta = __expf(2.0f * fmaf(alpha, dx, bxs));
        float cwv = 1.0f - 2.0f * __builtin_amdgcn_rcpf(ta + 1.0f);

#pragma unroll
        for (int t = 0; t < 4; ++t) {
            float4v av = acc[t];
#pragma unroll
            for (int r = 0; r < 4; ++r) {
                float mn = fmaf((ms[4 * t + r] - mu) * rstd, gr[4 * t + r], br[4 * t + r]);
                av[r] = fmaf(mn, alpha, av[r]);
            }
            acc[t] = av;
        }
        float rc = inv * cwv * validf * g0;
        ax0 = fmaf(r0, rc, ax0);
        ax1 = fmaf(r1, rc, ax1);
        ax2 = fmaf(r2, rc, ax2);
    }

    // reduce acc over the 16 edge-columns (4 shfl levels within 16-lane groups)
#pragma unroll
    for (int t = 0; t < 4; ++t) {
        float4v av = acc[t];
#pragma unroll
        for (int r = 0; r < 4; ++r) {
            float v = av[r];
#pragma unroll
            for (int mk = 1; mk < 16; mk <<= 1) v += __shfl_xor(v, mk, 64);
            av[r] = v;
        }
        acc[t] = av;
    }
    if (e16 == 0) {
        int hg = lane >> 4;
        float* dstp = agg_h + (size_t)n * HID + hg * 4;
#pragma unroll
        for (int t = 0; t < 4; ++t)
            *(float4*)(dstp + t * 16) =
                make_float4(acc[t][0], acc[t][1], acc[t][2], acc[t][3]);
    }
    // ax partials live in lanes 0..15
#pragma unroll
    for (int mk = 1; mk < 16; mk <<= 1) {
        ax0 += __shfl_xor(ax0, mk, 64);
        ax1 += __shfl_xor(ax1, mk, 64);
        ax2 += __shfl_xor(ax2, mk, 64);
    }
    if (lane == 0) {
        agg_x[n * 3 + 0] = ax0;
        agg_x[n * 3 + 1] = ax1;
        agg_x[n * 3 + 2] = ax2;
    }
}

// ---------------------------------------------------------------------------
// Fallback edge kernel (atomic aggregation) — only if ws too small for CSR.
// ---------------------------------------------------------------------------
__global__ __launch_bounds__(256) void edge_kernel_atomic(
    const int* __restrict__ src, const int* __restrict__ dst,
    const float* __restrict__ x,
    const float* __restrict__ Ps, const float* __restrict__ Pd,
    const float* __restrict__ Wt1, const float* __restrict__ Wt2,
    const float* __restrict__ be1, const float* __restrict__ be2,
    const float* __restrict__ ln_g, const float* __restrict__ ln_b,
    const float* __restrict__ Wx, const float* __restrict__ bx,
    const float* __restrict__ Wg, const float* __restrict__ bg,
    float* __restrict__ agg_h, float* __restrict__ agg_x, int E) {
    int e = blockIdx.x * 256 + threadIdx.x;
    if (e >= E) return;
    int s = src[e], d = dst[e];
    float r0 = x[s * 3] - x[d * 3], r1 = x[s * 3 + 1] - x[d * 3 + 1], r2 = x[s * 3 + 2] - x[d * 3 + 2];
    float dsq = r0 * r0 + r1 * r1 + r2 * r2;
    float inv = 1.0f / (sqrtf(dsq) + 1e-8f);
    float rn0 = r0 * inv, rn1 = r1 * inv, rn2 = r2 * inv;
    float z[HID];
    const float4* ps = (const float4*)(Ps + (size_t)s * HID);
    const float4* pd = (const float4*)(Pd + (size_t)d * HID);
    const float* colW = Wt1 + 256 * HID;
#pragma unroll
    for (int f4 = 0; f4 < HID / 4; ++f4) {
        float4 aa = ps[f4];
        float4 b = pd[f4];
        float av[4] = {aa.x, aa.y, aa.z, aa.w};
        float bv[4] = {b.x, b.y, b.z, b.w};
#pragma unroll
        for (int j = 0; j < 4; ++j) {
            int f = 4 * f4 + j;
            z[f] = silu_f(av[j] + bv[j] + be1[f] + dsq * colW[f]);
        }
    }
    float m[HID];
#pragma unroll
    for (int f = 0; f < HID; ++f) m[f] = be2[f];
#pragma unroll
    for (int k = 0; k < HID; ++k) {
        float zv = z[k];
#pragma unroll
        for (int f = 0; f < HID; ++f) m[f] = fmaf(zv, Wt2[k * HID + f], m[f]);
    }
#pragma unroll
    for (int f = 0; f < HID; ++f) m[f] = silu_f(m[f]);
    float mu = 0.f;
#pragma unroll
    for (int f = 0; f < HID; ++f) mu += m[f];
    mu *= (1.0f / HID);
    float var = 0.f;
#pragma unroll
    for (int f = 0; f < HID; ++f) {
        float t = m[f] - mu;
        var = fmaf(t, t, var);
    }
    var *= (1.0f / HID);
    float rstd = 1.0f / sqrtf(var + 1e-5f);
#pragma unroll
    for (int f = 0; f < HID; ++f) m[f] = (m[f] - mu) * rstd * ln_g[f] + ln_b[f];
    float dotg = 0.f, dotx = 0.f;
#pragma unroll
    for (int f = 0; f < HID; ++f) {
        dotg = fmaf(m[f], Wg[f], dotg);
        dotx = fmaf(m[f], Wx[f], dotx);
    }
    float alpha = 1.0f / (1.0f + __expf(-(dotg + bg[0])));
    float ta = __expf(2.0f * fmaf(alpha, dotx, bx[0]));
    float cw = 1.0f - 2.0f / (ta + 1.0f);
    float* ah = agg_h + (size_t)d * HID;
#pragma unroll
    for (int f = 0; f < HID; ++f) atomicAdd(&ah[f], m[f] * alpha);
    atomicAdd(&agg_x[d * 3 + 0], rn0 * cw);
    atomicAdd(&agg_x[d * 3 + 1], rn1 * cw);
    atomicAdd(&agg_x[d * 3 + 2], rn2 * cw);
}

// ---------------------------------------------------------------------------
// node_kernel (wave-feature-split, LDS hh exchange)
// ---------------------------------------------------------------------------
__global__ __launch_bounds__(256) void node_kernel(
    const float* __restrict__ h, const float* __restrict__ x,
    const float* __restrict__ agg_h, const float* __restrict__ agg_x,
    const int* __restrict__ degI,
    const float* __restrict__ Wht1, const float* __restrict__ Wht2,
    const float* __restrict__ bh1, const float* __restrict__ bh2,
    float* __restrict__ out, int N) {
    __shared__ float hh[64 * 65];
    int lane = threadIdx.x & 63;
    int w = __builtin_amdgcn_readfirstlane(threadIdx.x >> 6);
    int n = blockIdx.x * 64 + lane;

    if (n < N) {
        int f0 = w * 16;
        float t[16];
#pragma unroll
        for (int j = 0; j < 16; ++j) t[j] = bh1[f0 + j];
        const float4* rowH = (const float4*)(h + (size_t)n * DF);
        for (int k4 = 0; k4 < DF / 4; ++k4) {
            float4 v = rowH[k4];
            float hv4[4] = {v.x, v.y, v.z, v.w};
#pragma unroll
            for (int jj = 0; jj < 4; ++jj) {
                int k = k4 * 4 + jj;
                float hv = hv4[jj];
#pragma unroll
                for (int j = 0; j < 16; ++j) t[j] = fmaf(hv, Wht1[k * HID + f0 + j], t[j]);
            }
        }
        const float4* rowA = (const float4*)(agg_h + (size_t)n * HID);
        for (int k4 = 0; k4 < HID / 4; ++k4) {
            float4 v = rowA[k4];
            float hv4[4] = {v.x, v.y, v.z, v.w};
#pragma unroll
            for (int jj = 0; jj < 4; ++jj) {
                int k = DF + k4 * 4 + jj;
                float hv = hv4[jj];
#pragma unroll
                for (int j = 0; j < 16; ++j) t[j] = fmaf(hv, Wht1[k * HID + f0 + j], t[j]);
            }
        }
#pragma unroll
        for (int j = 0; j < 16; ++j) hh[lane * 65 + f0 + j] = silu_f(t[j]);
    }
    __syncthreads();
    if (n >= N) return;

    int c0 = w * 32;
    float o[32];
#pragma unroll
    for (int j = 0; j < 32; ++j) o[j] = bh2[c0 + j];
    for (int k = 0; k < HID; ++k) {
        float hv = hh[lane * 65 + k];
#pragma unroll
        for (int j = 0; j < 32; ++j) o[j] = fmaf(hv, Wht2[k * DF + c0 + j], o[j]);
    }
    float* oh = out + (size_t)n * DF + c0;
    const float* hrow = h + (size_t)n * DF + c0;
#pragma unroll
    for (int j4 = 0; j4 < 8; ++j4) {
        float4 hv = ((const float4*)hrow)[j4];
        float4 r;
        r.x = hv.x + o[4 * j4];
        r.y = hv.y + o[4 * j4 + 1];
        r.z = hv.z + o[4 * j4 + 2];
        r.w = hv.w + o[4 * j4 + 3];
        ((float4*)oh)[j4] = r;
    }
    if (w == 0) {
        float dv = (float)degI[n];
        float invd = 1.0f / fmaxf(dv, 1.0f);
        float* ox = out + (size_t)N * DF + (size_t)n * 3;
        ox[0] = x[n * 3 + 0] + agg_x[n * 3 + 0] * invd;
        ox[1] = x[n * 3 + 1] + agg_x[n * 3 + 1] * invd;
        ox[2] = x[n * 3 + 2] + agg_x[n * 3 + 2] * invd;
    }
}

extern "C" void kernel_launch(void* const* d_in, const int* in_sizes, int n_in,
                              void* d_out, int out_size, void* d_ws, size_t ws_size,
                              hipStream_t stream) {
    const float* h    = (const float*)d_in[0];
    const float* x    = (const float*)d_in[1];
    const int*   ei   = (const int*)d_in[2];
    const float* We1  = (const float*)d_in[3];
    const float* be1  = (const float*)d_in[4];
    const float* We2  = (const float*)d_in[5];
    const float* be2  = (const float*)d_in[6];
    const float* ln_g = (const float*)d_in[7];
    const float* ln_b = (const float*)d_in[8];
    const float* Wh1  = (const float*)d_in[9];
    const float* bh1  = (const float*)d_in[10];
    const float* Wh2  = (const float*)d_in[11];
    const float* bh2  = (const float*)d_in[12];
    const float* Wx   = (const float*)d_in[13];
    const float* bx   = (const float*)d_in[14];
    const float* Wg   = (const float*)d_in[15];
    const float* bg   = (const float*)d_in[16];

    const int E = in_sizes[2] / 2;
    const int N = in_sizes[0] / DF;
    const int* src = ei;
    const int* dst = ei + E;

    // ---- workspace carve (16B aligned regions) ----
    char* base = (char*)d_ws;
    size_t o = 0;
    auto carve = [&](size_t bytes) -> void* {
        void* r = base + o;
        o = (o + bytes + 15) & ~(size_t)15;
        return r;
    };
    float* agg_h = (float*)carve((size_t)N * HID * 4);
    float* agg_x = (float*)carve((size_t)N * 3 * 4);
    float* Wt1   = (float*)carve(257 * 64 * 4);
    float* Wt2   = (float*)carve(64 * 64 * 4);
    float* Wht1  = (float*)carve(192 * 64 * 4);
    float* Wht2  = (float*)carve(64 * 128 * 4);
    unsigned short* WbfA = (unsigned short*)carve(4096 * 2);
    int*   cnt   = (int*)carve((size_t)N * 4);
    int*   off   = (int*)carve(((size_t)N + 1) * 4);
    int*   bsum  = (int*)carve(256 * 4);
    int*   bofs  = (int*)carve(256 * 4);
    int*   dcnt  = (int*)carve(64 * 4);
    int*   dofs  = (int*)carve(64 * 4);
    int*   dnr   = (int*)carve((size_t)N * 4);
    int*   nodeorder = (int*)carve((size_t)N * 4);
    int*   rank  = (int*)carve((size_t)E * 4);
    int*   csr_src = (int*)carve((size_t)E * 4);
    size_t need_full = o;

    // Ps/Pd live in d_out (N*128 <= out_size N*131); fully overwritten later.
    float* Ps = (float*)d_out;
    float* Pd = Ps + (size_t)N * HID;

    const int gE  = (E + 255) / 256;
    const int Nb  = (N + 1023) / 1024;
    const int gN64 = (N + 63) / 64;

    hipMemsetAsync(cnt, 0, (size_t)N * 4, stream);
    prep_weights<<<(45120 + 255) / 256, 256, 0, stream>>>(We1, We2, Wh1, Wh2,
                                                          Wt1, Wt2, Wht1, Wht2, WbfA);
    node_pre<<<gN64, 256, 0, stream>>>(h, Wt1, Ps, Pd, N);

    if (ws_size >= need_full) {
        // ---- CSR build ----
        hipMemsetAsync(dcnt, 0, 64 * 4, stream);
        count_kernel<<<gE, 256, 0, stream>>>(dst, cnt, rank, E);
        scan1<<<Nb, 1024, 0, stream>>>(cnt, off, bsum, N);
        scan2<<<1, 64, 0, stream>>>(bsum, bofs, Nb);
        scan3<<<(N + 256) / 256, 256, 0, stream>>>(off, bofs, N, E);
        scatter_src<<<gE, 256, 0, stream>>>(dst, src, rank, off, csr_src, E);
        deghist<<<(N + 255) / 256, 256, 0, stream>>>(cnt, dcnt, dnr, N);
        degscan<<<1, 64, 0, stream>>>(dcnt, dofs);
        degscatter<<<(N + 255) / 256, 256, 0, stream>>>(cnt, dnr, dofs, nodeorder, N);
        // ---- fused gather: one wave per node, 16 edges per MFMA batch ----
        gather_kernel<<<(N + 3) / 4, 256, 0, stream>>>(
            csr_src, off, nodeorder, x, Ps, Pd, Wt1, WbfA, be1, be2,
            ln_g, ln_b, Wx, bx, Wg, bg, agg_h, agg_x, N);
    } else {
        // ---- fallback: atomic aggregation ----
        hipMemsetAsync(agg_h, 0, (size_t)N * 67 * 4, stream);
        count_kernel<<<gE, 256, 0, stream>>>(dst, cnt, nullptr, E);
        edge_kernel_atomic<<<gE, 256, 0, stream>>>(src, dst, x, Ps, Pd, Wt1, Wt2,
                                                   be1, be2, ln_g, ln_b, Wx, bx,
                                                   Wg, bg, agg_h, agg_x, E);
    }

    node_kernel<<<gN64, 256, 0, stream>>>(h, x, agg_h, agg_x, cnt,
                                          Wht1, Wht2, bh1, bh2, (float*)d_out, N);
}

// Round 9
// 333.543 us; speedup vs baseline: 3.4922x; 1.3989x over previous
//
#include <hip/hip_runtime.h>
#include <math.h>

#define HID 64
#define DF  128

typedef __attribute__((ext_vector_type(8))) short short8v;   // 8 bf16
typedef __attribute__((ext_vector_type(4))) float float4v;

__device__ __forceinline__ float silu_f(float v) {
    return v * __builtin_amdgcn_rcpf(1.0f + __expf(-v));
}

__device__ __forceinline__ unsigned short f2bf(float f) {   // RNE f32->bf16
    unsigned u = __float_as_uint(f);
    u += 0x7FFFu + ((u >> 16) & 1u);
    return (unsigned short)(u >> 16);
}

// 4 simultaneous wave-wide sums: one 6-level tree, 4-way ILP per level
__device__ __forceinline__ void wredsum4(float& a, float& b, float& c, float& d) {
#pragma unroll
    for (int t = 1; t < 64; t <<= 1) {
        a += __shfl_xor(a, t, 64);
        b += __shfl_xor(b, t, 64);
        c += __shfl_xor(c, t, 64);
        d += __shfl_xor(d, t, 64);
    }
}

// ---------------------------------------------------------------------------
// Weight transposes + bf16 MFMA A-fragment pack of We2.
// WbfA flat j = ((t*2+kc)*64 + lane)*8 + jj  = bf16(We2[t*16+(lane&15)][kc*32+(lane>>4)*8+jj])
// ---------------------------------------------------------------------------
__global__ void prep_weights(const float* __restrict__ We1, const float* __restrict__ We2,
                             const float* __restrict__ Wh1, const float* __restrict__ Wh2,
                             float* __restrict__ Wt1, float* __restrict__ Wt2,
                             float* __restrict__ Wht1, float* __restrict__ Wht2,
                             unsigned short* __restrict__ WbfA) {
    int i = blockIdx.x * 256 + threadIdx.x;
    if (i < 257 * 64) {
        int k = i >> 6, f = i & 63;
        Wt1[i] = We1[f * 257 + k];
        return;
    }
    int j = i - 257 * 64;
    if (j < 64 * 64) {
        int k = j >> 6, f = j & 63;
        Wt2[j] = We2[f * 64 + k];
        return;
    }
    j -= 64 * 64;
    if (j < 192 * 64) {
        int k = j >> 6, f = j & 63;
        Wht1[j] = Wh1[f * 192 + k];
        return;
    }
    j -= 192 * 64;
    if (j < 64 * 128) {
        int f = j >> 7, c = j & 127;
        Wht2[j] = Wh2[c * 64 + f];
        return;
    }
    j -= 64 * 128;
    if (j < 4096) {
        int jj = j & 7, lane = (j >> 3) & 63, kc = (j >> 9) & 1, t = (j >> 10) & 3;
        int f = t * 16 + (lane & 15);
        int k = kc * 32 + ((lane >> 4) * 8) + jj;
        WbfA[j] = f2bf(We2[f * 64 + k]);
        return;
    }
}

// ---------------------------------------------------------------------------
// CSR build
// ---------------------------------------------------------------------------
__global__ __launch_bounds__(256) void count_kernel(const int* __restrict__ dst,
                                                    int* __restrict__ cnt,
                                                    int* __restrict__ rank, int E) {
    int e = blockIdx.x * 256 + threadIdx.x;
    if (e >= E) return;
    int r = atomicAdd(&cnt[dst[e]], 1);
    if (rank) rank[e] = r;
}

__global__ __launch_bounds__(1024) void scan1(const int* __restrict__ cnt,
                                              int* __restrict__ off,
                                              int* __restrict__ bsum, int N) {
    __shared__ int sm[1024];
    int tid = threadIdx.x;
    int i = blockIdx.x * 1024 + tid;
    int v = (i < N) ? cnt[i] : 0;
    sm[tid] = v;
    __syncthreads();
    for (int ofs = 1; ofs < 1024; ofs <<= 1) {
        int t = (tid >= ofs) ? sm[tid - ofs] : 0;
        __syncthreads();
        sm[tid] += t;
        __syncthreads();
    }
    if (i < N) off[i] = sm[tid] - v;
    if (tid == 1023) bsum[blockIdx.x] = sm[1023];
}

// scan3 with scan2 folded in: each block prefix-sums bsum (<=64 entries) itself
__global__ __launch_bounds__(256) void scan3(int* __restrict__ off,
                                             const int* __restrict__ bsum,
                                             int Nb, int N, int E) {
    __shared__ int pref[64];
    if (threadIdx.x == 0) {
        int s = 0;
        for (int b = 0; b < Nb; ++b) { pref[b] = s; s += bsum[b]; }
    }
    __syncthreads();
    int i = blockIdx.x * 256 + threadIdx.x;
    if (i > N) return;
    if (i == N) off[N] = E;
    else off[i] += pref[i >> 10];
}

__global__ __launch_bounds__(256) void scatter_src(const int* __restrict__ dst,
                                                   const int* __restrict__ srcI,
                                                   const int* __restrict__ rank,
                                                   const int* __restrict__ off,
                                                   int* __restrict__ csr_src, int E) {
    int e = blockIdx.x * 256 + threadIdx.x;
    if (e >= E) return;
    csr_src[off[dst[e]] + rank[e]] = srcI[e];
}

// ---------------------------------------------------------------------------
// node_pre (wave-feature-split): 4 waves over 64 nodes; wave w does 16 feats.
// NOTE: be1 is BAKED into Pd here (Pd' = h@Wdst^T + be1).
// ---------------------------------------------------------------------------
__global__ __launch_bounds__(256) void node_pre(const float* __restrict__ h,
                                                const float* __restrict__ Wt1,
                                                const float* __restrict__ be1,
                                                float* __restrict__ Ps,
                                                float* __restrict__ Pd, int N) {
    int lane = threadIdx.x & 63;
    int w = __builtin_amdgcn_readfirstlane(threadIdx.x >> 6);
    int n = blockIdx.x * 64 + lane;
    if (n >= N) return;
    int f0 = w * 16;
    float accS[16], accD[16];
#pragma unroll
    for (int j = 0; j < 16; ++j) { accS[j] = 0.f; accD[j] = be1[f0 + j]; }
    const float4* row = (const float4*)(h + (size_t)n * DF);
    for (int k4 = 0; k4 < DF / 4; ++k4) {
        float4 v = row[k4];
        float hv4[4] = {v.x, v.y, v.z, v.w};
#pragma unroll
        for (int jj = 0; jj < 4; ++jj) {
            int k = k4 * 4 + jj;
            float hv = hv4[jj];
#pragma unroll
            for (int j = 0; j < 16; ++j) {
                accS[j] = fmaf(hv, Wt1[k * HID + f0 + j], accS[j]);
                accD[j] = fmaf(hv, Wt1[(DF + k) * HID + f0 + j], accD[j]);
            }
        }
    }
    float4* ps = (float4*)(Ps + (size_t)n * HID + f0);
    float4* pd = (float4*)(Pd + (size_t)n * HID + f0);
#pragma unroll
    for (int j4 = 0; j4 < 4; ++j4) {
        ps[j4] = make_float4(accS[4 * j4], accS[4 * j4 + 1], accS[4 * j4 + 2], accS[4 * j4 + 3]);
        pd[j4] = make_float4(accD[4 * j4], accD[4 * j4 + 1], accD[4 * j4 + 2], accD[4 * j4 + 3]);
    }
}

// ---------------------------------------------------------------------------
// Gather v6: grid-stride waves over nodes; 16 edges per bf16-MFMA batch.
//  B-fragments computed DIRECTLY per lane (no LDS staging, no barriers):
//  lane (e16,hg) builds z[k0..k0+7]+z[k0+32..+7] of its own edge from 4
//  float4 Ps loads. A-frags + all params resident across the node loop.
// ---------------------------------------------------------------------------
__global__ __launch_bounds__(256) void gather_kernel(
    const int* __restrict__ csr_src, const int* __restrict__ off,
    const float* __restrict__ x,
    const float* __restrict__ Ps, const float* __restrict__ Pd,
    const float* __restrict__ Wt1, const unsigned short* __restrict__ WbfA,
    const float* __restrict__ be2,
    const float* __restrict__ ln_g, const float* __restrict__ ln_b,
    const float* __restrict__ Wx, const float* __restrict__ bx,
    const float* __restrict__ Wg, const float* __restrict__ bg,
    float* __restrict__ agg_h, float* __restrict__ agg_x, int N, int nwaves) {
    const int lane = threadIdx.x & 63;
    const int wid = blockIdx.x * 4 + (threadIdx.x >> 6);
    const int e16 = lane & 15;
    const int hg = lane >> 4;
    const int k0 = hg * 8;

    // resident A fragments (We2 bf16)
    short8v a[4][2];
#pragma unroll
    for (int t = 0; t < 4; ++t)
#pragma unroll
        for (int kc = 0; kc < 2; ++kc)
            a[t][kc] = *(const short8v*)&WbfA[(((t * 2 + kc) * 64) + lane) * 8];

    // z-side per-lane k-chunk constants (k = k0+j and k0+32+j)
    const float* colW = Wt1 + 256 * HID;
    float colWk[16];
#pragma unroll
    for (int j = 0; j < 8; ++j) {
        colWk[j] = colW[k0 + j];
        colWk[8 + j] = colW[k0 + 32 + j];
    }
    // m-side per-lane params (f = t*16 + hg*4 + r)
    float be2r[16], gr[16], br[16], cgr[16], cxr[16];
#pragma unroll
    for (int t = 0; t < 4; ++t)
#pragma unroll
        for (int r = 0; r < 4; ++r) {
            int f = t * 16 + hg * 4 + r;
            float g = ln_g[f];
            be2r[4 * t + r] = be2[f];
            gr[4 * t + r] = g;
            br[4 * t + r] = ln_b[f];
            cgr[4 * t + r] = g * Wg[f];
            cxr[4 * t + r] = g * Wx[f];
        }
    const float bgs = bg[0], bxs = bx[0];

    // wave-uniform loop invariants (feature=lane view)
    float Cg = ln_g[lane] * Wg[lane], Cx = ln_g[lane] * Wx[lane];
    float Cbg = ln_b[lane] * Wg[lane], Cbx = ln_b[lane] * Wx[lane];
    wredsum4(Cg, Cx, Cbg, Cbx);
    const float g0 = (lane < 16) ? 1.0f : 0.0f;

    for (int n = wid; n < N; n += nwaves) {
        const int beg = off[n], end = off[n + 1];
        const float xd0 = x[n * 3], xd1 = x[n * 3 + 1], xd2 = x[n * 3 + 2];
        // per-node z-base (Pd already includes be1)
        float baseK[16];
        {
            const float4v* pd4 = (const float4v*)(Pd + (size_t)n * HID + k0);
            float4v p0 = pd4[0], p1 = pd4[1], p2 = pd4[8], p3 = pd4[9];
#pragma unroll
            for (int j = 0; j < 4; ++j) {
                baseK[j] = p0[j];
                baseK[4 + j] = p1[j];
                baseK[8 + j] = p2[j];
                baseK[12 + j] = p3[j];
            }
        }

        float4v acc[4];
#pragma unroll
        for (int t = 0; t < 4; ++t) acc[t] = (float4v){0.f, 0.f, 0.f, 0.f};
        float ax0 = 0.f, ax1 = 0.f, ax2 = 0.f;

        for (int base = beg; base < end; base += 16) {
            int idx = base + e16;
            float validf = (idx < end) ? 1.0f : 0.0f;
            int idxc = (idx < end) ? idx : (end - 1);
            int s = csr_src[idxc];
            float r0 = x[s * 3] - xd0, r1 = x[s * 3 + 1] - xd1, r2 = x[s * 3 + 2] - xd2;
            float dsq = r0 * r0 + r1 * r1 + r2 * r2;
            float inv = __builtin_amdgcn_rcpf(__builtin_amdgcn_sqrtf(dsq) + 1e-8f);

            // direct B-fragments: z for this lane's edge, k-chunks k0 / k0+32
            const float4v* ps4 = (const float4v*)(Ps + (size_t)s * HID + k0);
            float4v q0 = ps4[0], q1 = ps4[1], q2 = ps4[8], q3 = ps4[9];
            short8v b0, b1;
#pragma unroll
            for (int j = 0; j < 4; ++j) {
                float z0 = q0[j] + baseK[j] + dsq * colWk[j];
                float z1 = q1[j] + baseK[4 + j] + dsq * colWk[4 + j];
                float z2 = q2[j] + baseK[8 + j] + dsq * colWk[8 + j];
                float z3 = q3[j] + baseK[12 + j] + dsq * colWk[12 + j];
                b0[j]     = (short)f2bf(silu_f(z0));
                b0[4 + j] = (short)f2bf(silu_f(z1));
                b1[j]     = (short)f2bf(silu_f(z2));
                b1[4 + j] = (short)f2bf(silu_f(z3));
            }

            float4v d[4];
#pragma unroll
            for (int t = 0; t < 4; ++t) {
                float4v c = (float4v){0.f, 0.f, 0.f, 0.f};
                c = __builtin_amdgcn_mfma_f32_16x16x32_bf16(a[t][0], b0, c, 0, 0, 0);
                c = __builtin_amdgcn_mfma_f32_16x16x32_bf16(a[t][1], b1, c, 0, 0, 0);
                d[t] = c;
            }

            // bias + silu + partial stats (lane's 16 rows of edge e16)
            float ms[16];
            float S1 = 0.f, S2 = 0.f, Sg = 0.f, Sx = 0.f;
#pragma unroll
            for (int t = 0; t < 4; ++t)
#pragma unroll
                for (int r = 0; r < 4; ++r) {
                    float mp = d[t][r] + be2r[4 * t + r];
                    float v = mp * __builtin_amdgcn_rcpf(1.0f + __expf(-mp));
                    ms[4 * t + r] = v;
                    S1 += v;
                    S2 = fmaf(v, v, S2);
                    Sg = fmaf(v, cgr[4 * t + r], Sg);
                    Sx = fmaf(v, cxr[4 * t + r], Sx);
                }
            // complete per-edge sums across the 4 row-groups (2 shfl levels)
#pragma unroll
            for (int mk = 16; mk < 64; mk <<= 1) {
                S1 += __shfl_xor(S1, mk, 64);
                S2 += __shfl_xor(S2, mk, 64);
                Sg += __shfl_xor(Sg, mk, 64);
                Sx += __shfl_xor(Sx, mk, 64);
            }

            float mu = S1 * (1.0f / HID);
            float var = S2 * (1.0f / HID) - mu * mu;
            float rstd = __builtin_amdgcn_rsqf(var + 1e-5f);
            float dg = fmaf(rstd, Sg - mu * Cg, Cbg);
            float dx = fmaf(rstd, Sx - mu * Cx, Cbx);
            float alpha = __builtin_amdgcn_rcpf(1.0f + __expf(-(dg + bgs))) * validf;
            float ta = __expf(2.0f * fmaf(alpha, dx, bxs));
            float cwv = 1.0f - 2.0f * __builtin_amdgcn_rcpf(ta + 1.0f);

#pragma unroll
            for (int t = 0; t < 4; ++t) {
                float4v av = acc[t];
#pragma unroll
                for (int r = 0; r < 4; ++r) {
                    float mn = fmaf((ms[4 * t + r] - mu) * rstd, gr[4 * t + r], br[4 * t + r]);
                    av[r] = fmaf(mn, alpha, av[r]);
                }
                acc[t] = av;
            }
            float rc = inv * cwv * validf * g0;
            ax0 = fmaf(r0, rc, ax0);
            ax1 = fmaf(r1, rc, ax1);
            ax2 = fmaf(r2, rc, ax2);
        }

        // reduce acc over the 16 edge-columns (4 shfl levels within 16-lane groups)
#pragma unroll
        for (int t = 0; t < 4; ++t) {
            float4v av = acc[t];
#pragma unroll
            for (int r = 0; r < 4; ++r) {
                float v = av[r];
#pragma unroll
                for (int mk = 1; mk < 16; mk <<= 1) v += __shfl_xor(v, mk, 64);
                av[r] = v;
            }
            acc[t] = av;
        }
        if (e16 == 0) {
            float* dstp = agg_h + (size_t)n * HID + hg * 4;
#pragma unroll
            for (int t = 0; t < 4; ++t)
                *(float4*)(dstp + t * 16) =
                    make_float4(acc[t][0], acc[t][1], acc[t][2], acc[t][3]);
        }
        float bx0 = ax0, bx1 = ax1, bx2 = ax2;
#pragma unroll
        for (int mk = 1; mk < 16; mk <<= 1) {
            bx0 += __shfl_xor(bx0, mk, 64);
            bx1 += __shfl_xor(bx1, mk, 64);
            bx2 += __shfl_xor(bx2, mk, 64);
        }
        if (lane == 0) {
            agg_x[n * 3 + 0] = bx0;
            agg_x[n * 3 + 1] = bx1;
            agg_x[n * 3 + 2] = bx2;
        }
    }
}

// ---------------------------------------------------------------------------
// Fallback edge kernel (atomic aggregation) — only if ws too small for CSR.
// (Pd includes be1 now.)
// ---------------------------------------------------------------------------
__global__ __launch_bounds__(256) void edge_kernel_atomic(
    const int* __restrict__ src, const int* __restrict__ dst,
    const float* __restrict__ x,
    const float* __restrict__ Ps, const float* __restrict__ Pd,
    const float* __restrict__ Wt1, const float* __restrict__ Wt2,
    const float* __restrict__ be2,
    const float* __restrict__ ln_g, const float* __restrict__ ln_b,
    const float* __restrict__ Wx, const float* __restrict__ bx,
    const float* __restrict__ Wg, const float* __restrict__ bg,
    float* __restrict__ agg_h, float* __restrict__ agg_x, int E) {
    int e = blockIdx.x * 256 + threadIdx.x;
    if (e >= E) return;
    int s = src[e], d = dst[e];
    float r0 = x[s * 3] - x[d * 3], r1 = x[s * 3 + 1] - x[d * 3 + 1], r2 = x[s * 3 + 2] - x[d * 3 + 2];
    float dsq = r0 * r0 + r1 * r1 + r2 * r2;
    float inv = 1.0f / (sqrtf(dsq) + 1e-8f);
    float rn0 = r0 * inv, rn1 = r1 * inv, rn2 = r2 * inv;
    float z[HID];
    const float4* ps = (const float4*)(Ps + (size_t)s * HID);
    const float4* pd = (const float4*)(Pd + (size_t)d * HID);
    const float* colW = Wt1 + 256 * HID;
#pragma unroll
    for (int f4 = 0; f4 < HID / 4; ++f4) {
        float4 aa = ps[f4];
        float4 b = pd[f4];
        float av[4] = {aa.x, aa.y, aa.z, aa.w};
        float bv[4] = {b.x, b.y, b.z, b.w};
#pragma unroll
        for (int j = 0; j < 4; ++j) {
            int f = 4 * f4 + j;
            z[f] = silu_f(av[j] + bv[j] + dsq * colW[f]);
        }
    }
    float m[HID];
#pragma unroll
    for (int f = 0; f < HID; ++f) m[f] = be2[f];
#pragma unroll
    for (int k = 0; k < HID; ++k) {
        float zv = z[k];
#pragma unroll
        for (int f = 0; f < HID; ++f) m[f] = fmaf(zv, Wt2[k * HID + f], m[f]);
    }
#pragma unroll
    for (int f = 0; f < HID; ++f) m[f] = silu_f(m[f]);
    float mu = 0.f;
#pragma unroll
    for (int f = 0; f < HID; ++f) mu += m[f];
    mu *= (1.0f / HID);
    float var = 0.f;
#pragma unroll
    for (int f = 0; f < HID; ++f) {
        float t = m[f] - mu;
        var = fmaf(t, t, var);
    }
    var *= (1.0f / HID);
    float rstd = 1.0f / sqrtf(var + 1e-5f);
#pragma unroll
    for (int f = 0; f < HID; ++f) m[f] = (m[f] - mu) * rstd * ln_g[f] + ln_b[f];
    float dotg = 0.f, dotx = 0.f;
#pragma unroll
    for (int f = 0; f < HID; ++f) {
        dotg = fmaf(m[f], Wg[f], dotg);
        dotx = fmaf(m[f], Wx[f], dotx);
    }
    float alpha = 1.0f / (1.0f + __expf(-(dotg + bg[0])));
    float ta = __expf(2.0f * fmaf(alpha, dotx, bx[0]));
    float cw = 1.0f - 2.0f / (ta + 1.0f);
    float* ah = agg_h + (size_t)d * HID;
#pragma unroll
    for (int f = 0; f < HID; ++f) atomicAdd(&ah[f], m[f] * alpha);
    atomicAdd(&agg_x[d * 3 + 0], rn0 * cw);
    atomicAdd(&agg_x[d * 3 + 1], rn1 * cw);
    atomicAdd(&agg_x[d * 3 + 2], rn2 * cw);
}

// ---------------------------------------------------------------------------
// node_kernel (wave-feature-split, LDS hh exchange)
// ---------------------------------------------------------------------------
__global__ __launch_bounds__(256) void node_kernel(
    const float* __restrict__ h, const float* __restrict__ x,
    const float* __restrict__ agg_h, const float* __restrict__ agg_x,
    const int* __restrict__ degI,
    const float* __restrict__ Wht1, const float* __restrict__ Wht2,
    const float* __restrict__ bh1, const float* __restrict__ bh2,
    float* __restrict__ out, int N) {
    __shared__ float hh[64 * 65];
    int lane = threadIdx.x & 63;
    int w = __builtin_amdgcn_readfirstlane(threadIdx.x >> 6);
    int n = blockIdx.x * 64 + lane;

    if (n < N) {
        int f0 = w * 16;
        float t[16];
#pragma unroll
        for (int j = 0; j < 16; ++j) t[j] = bh1[f0 + j];
        const float4* rowH = (const float4*)(h + (size_t)n * DF);
        for (int k4 = 0; k4 < DF / 4; ++k4) {
            float4 v = rowH[k4];
            float hv4[4] = {v.x, v.y, v.z, v.w};
#pragma unroll
            for (int jj = 0; jj < 4; ++jj) {
                int k = k4 * 4 + jj;
                float hv = hv4[jj];
#pragma unroll
                for (int j = 0; j < 16; ++j) t[j] = fmaf(hv, Wht1[k * HID + f0 + j], t[j]);
            }
        }
        const float4* rowA = (const float4*)(agg_h + (size_t)n * HID);
        for (int k4 = 0; k4 < HID / 4; ++k4) {
            float4 v = rowA[k4];
            float hv4[4] = {v.x, v.y, v.z, v.w};
#pragma unroll
            for (int jj = 0; jj < 4; ++jj) {
                int k = DF + k4 * 4 + jj;
                float hv = hv4[jj];
#pragma unroll
                for (int j = 0; j < 16; ++j) t[j] = fmaf(hv, Wht1[k * HID + f0 + j], t[j]);
            }
        }
#pragma unroll
        for (int j = 0; j < 16; ++j) hh[lane * 65 + f0 + j] = silu_f(t[j]);
    }
    __syncthreads();
    if (n >= N) return;

    int c0 = w * 32;
    float o[32];
#pragma unroll
    for (int j = 0; j < 32; ++j) o[j] = bh2[c0 + j];
    for (int k = 0; k < HID; ++k) {
        float hv = hh[lane * 65 + k];
#pragma unroll
        for (int j = 0; j < 32; ++j) o[j] = fmaf(hv, Wht2[k * DF + c0 + j], o[j]);
    }
    float* oh = out + (size_t)n * DF + c0;
    const float* hrow = h + (size_t)n * DF + c0;
#pragma unroll
    for (int j4 = 0; j4 < 8; ++j4) {
        float4 hv = ((const float4*)hrow)[j4];
        float4 r;
        r.x = hv.x + o[4 * j4];
        r.y = hv.y + o[4 * j4 + 1];
        r.z = hv.z + o[4 * j4 + 2];
        r.w = hv.w + o[4 * j4 + 3];
        ((float4*)oh)[j4] = r;
    }
    if (w == 0) {
        float dv = (float)degI[n];
        float invd = 1.0f / fmaxf(dv, 1.0f);
        float* ox = out + (size_t)N * DF + (size_t)n * 3;
        ox[0] = x[n * 3 + 0] + agg_x[n * 3 + 0] * invd;
        ox[1] = x[n * 3 + 1] + agg_x[n * 3 + 1] * invd;
        ox[2] = x[n * 3 + 2] + agg_x[n * 3 + 2] * invd;
    }
}

extern "C" void kernel_launch(void* const* d_in, const int* in_sizes, int n_in,
                              void* d_out, int out_size, void* d_ws, size_t ws_size,
                              hipStream_t stream) {
    const float* h    = (const float*)d_in[0];
    const float* x    = (const float*)d_in[1];
    const int*   ei   = (const int*)d_in[2];
    const float* We1  = (const float*)d_in[3];
    const float* be1  = (const float*)d_in[4];
    const float* We2  = (const float*)d_in[5];
    const float* be2  = (const float*)d_in[6];
    const float* ln_g = (const float*)d_in[7];
    const float* ln_b = (const float*)d_in[8];
    const float* Wh1  = (const float*)d_in[9];
    const float* bh1  = (const float*)d_in[10];
    const float* Wh2  = (const float*)d_in[11];
    const float* bh2  = (const float*)d_in[12];
    const float* Wx   = (const float*)d_in[13];
    const float* bx   = (const float*)d_in[14];
    const float* Wg   = (const float*)d_in[15];
    const float* bg   = (const float*)d_in[16];

    const int E = in_sizes[2] / 2;
    const int N = in_sizes[0] / DF;
    const int* src = ei;
    const int* dst = ei + E;

    // ---- workspace carve (16B aligned regions) ----
    char* base = (char*)d_ws;
    size_t o = 0;
    auto carve = [&](size_t bytes) -> void* {
        void* r = base + o;
        o = (o + bytes + 15) & ~(size_t)15;
        return r;
    };
    float* agg_h = (float*)carve((size_t)N * HID * 4);
    float* agg_x = (float*)carve((size_t)N * 3 * 4);
    float* Wt1   = (float*)carve(257 * 64 * 4);
    float* Wt2   = (float*)carve(64 * 64 * 4);
    float* Wht1  = (float*)carve(192 * 64 * 4);
    float* Wht2  = (float*)carve(64 * 128 * 4);
    unsigned short* WbfA = (unsigned short*)carve(4096 * 2);
    int*   cnt   = (int*)carve((size_t)N * 4);
    int*   off   = (int*)carve(((size_t)N + 1) * 4);
    int*   bsum  = (int*)carve(256 * 4);
    int*   rank  = (int*)carve((size_t)E * 4);
    int*   csr_src = (int*)carve((size_t)E * 4);
    size_t need_full = o;

    // Ps/Pd live in d_out (N*128 <= out_size N*131); fully overwritten later.
    float* Ps = (float*)d_out;
    float* Pd = Ps + (size_t)N * HID;

    const int gE  = (E + 255) / 256;
    const int Nb  = (N + 1023) / 1024;
    const int gN64 = (N + 63) / 64;

    hipMemsetAsync(cnt, 0, (size_t)N * 4, stream);
    prep_weights<<<(45120 + 255) / 256, 256, 0, stream>>>(We1, We2, Wh1, Wh2,
                                                          Wt1, Wt2, Wht1, Wht2, WbfA);
    node_pre<<<gN64, 256, 0, stream>>>(h, Wt1, be1, Ps, Pd, N);

    if (ws_size >= need_full) {
        // ---- CSR build (scan2 folded into scan3; no degree sort) ----
        count_kernel<<<gE, 256, 0, stream>>>(dst, cnt, rank, E);
        scan1<<<Nb, 1024, 0, stream>>>(cnt, off, bsum, N);
        scan3<<<(N + 256) / 256, 256, 0, stream>>>(off, bsum, Nb, N, E);
        scatter_src<<<gE, 256, 0, stream>>>(dst, src, rank, off, csr_src, E);
        // ---- fused gather: grid-stride waves, 16 edges per MFMA batch ----
        const int GBLK = 1024;              // 4096 waves, ~12 nodes each
        gather_kernel<<<GBLK, 256, 0, stream>>>(
            csr_src, off, x, Ps, Pd, Wt1, WbfA, be2,
            ln_g, ln_b, Wx, bx, Wg, bg, agg_h, agg_x, N, GBLK * 4);
    } else {
        // ---- fallback: atomic aggregation ----
        hipMemsetAsync(agg_h, 0, (size_t)N * 67 * 4, stream);
        count_kernel<<<gE, 256, 0, stream>>>(dst, cnt, nullptr, E);
        edge_kernel_atomic<<<gE, 256, 0, stream>>>(src, dst, x, Ps, Pd, Wt1, Wt2,
                                                   be2, ln_g, ln_b, Wx, bx,
                                                   Wg, bg, agg_h, agg_x, E);
    }

    node_kernel<<<gN64, 256, 0, stream>>>(h, x, agg_h, agg_x, cnt,
                                          Wht1, Wht2, bh1, bh2, (float*)d_out, N);
}